// Round 2
// baseline (415.169 us; speedup 1.0000x reference)
//
#include <hip/hip_runtime.h>
#include <math.h>

typedef float  f32x4 __attribute__((ext_vector_type(4)));
typedef short  s16x8 __attribute__((ext_vector_type(8)));
typedef short  s16x4 __attribute__((ext_vector_type(4)));
typedef unsigned short u16;
typedef unsigned int u32;

// ---------- bf16 helpers ----------
static __device__ __forceinline__ u16 f32_to_bf16_rne(float f) {
    u32 u = __builtin_bit_cast(u32, f);
    u32 r = u + 0x7fffu + ((u >> 16) & 1u);
    return (u16)(r >> 16);
}
static __device__ __forceinline__ u32 pack_bf16_rhu(float a, float b) {
    u32 ua = __builtin_bit_cast(u32, a);
    u32 ub = __builtin_bit_cast(u32, b);
    return ((ua + 0x8000u) >> 16) | ((ub + 0x8000u) & 0xffff0000u);
}
static __device__ __forceinline__ float bf16_to_f32(u16 h) {
    return __builtin_bit_cast(float, (u32)h << 16);
}

// async global->LDS 16B (lane-contiguous LDS dest ONLY; source is per-lane)
static __device__ __forceinline__ void gl2lds16(const void* g, void* l) {
    __builtin_amdgcn_global_load_lds(
        (const __attribute__((address_space(1))) u32*)g,
        (__attribute__((address_space(3))) u32*)l, 16, 0, 0);
}

// ---------- 1) cast fp32 -> bf16 ----------
__global__ __launch_bounds__(256) void k_cast(const float* __restrict__ in,
                                              u16* __restrict__ out) {
    int i = (blockIdx.x * 256 + threadIdx.x) * 8;
    float4 a = *reinterpret_cast<const float4*>(in + i);
    float4 b = *reinterpret_cast<const float4*>(in + i + 4);
    s16x8 o;
    o[0] = (short)f32_to_bf16_rne(a.x); o[1] = (short)f32_to_bf16_rne(a.y);
    o[2] = (short)f32_to_bf16_rne(a.z); o[3] = (short)f32_to_bf16_rne(a.w);
    o[4] = (short)f32_to_bf16_rne(b.x); o[5] = (short)f32_to_bf16_rne(b.y);
    o[6] = (short)f32_to_bf16_rne(b.z); o[7] = (short)f32_to_bf16_rne(b.w);
    *reinterpret_cast<s16x8*>(out + i) = o;
}

// ---------- 2) transpose + cast ----------
__global__ __launch_bounds__(256) void k_transpose_cast(const float* __restrict__ in,
                                                        u16* __restrict__ out,
                                                        int R, int C) {
    __shared__ float TT[64 * 130];
    const int t = threadIdx.x;
    const int ct = blockIdx.x, rt = blockIdx.y;
    const int tr = t >> 4;
    const int tc = t & 15;
    float4 v[8];
#pragma unroll
    for (int u = 0; u < 8; ++u) {
        int r = u * 16 + tr;
        v[u] = *reinterpret_cast<const float4*>(in + (size_t)(rt * 128 + r) * C + ct * 64 + tc * 4);
    }
#pragma unroll
    for (int u = 0; u < 8; ++u) {
        int r = u * 16 + tr;
        TT[(tc * 4 + 0) * 130 + r] = v[u].x;
        TT[(tc * 4 + 1) * 130 + r] = v[u].y;
        TT[(tc * 4 + 2) * 130 + r] = v[u].z;
        TT[(tc * 4 + 3) * 130 + r] = v[u].w;
    }
    __syncthreads();
#pragma unroll
    for (int u = 0; u < 4; ++u) {
        int oc = u * 16 + tr;
        int r0 = tc * 8;
        s16x8 o;
#pragma unroll
        for (int e = 0; e < 8; ++e)
            o[e] = (short)f32_to_bf16_rne(TT[oc * 130 + r0 + e]);
        *reinterpret_cast<s16x8*>(out + (size_t)(ct * 64 + oc) * R + rt * 128 + r0) = o;
    }
}

// ---------- 3a) m97-style 128x128 GEMM (kept for out-projection) ----------
template<bool BF16OUT, bool ROPE>
__global__ __launch_bounds__(256) void k_gemm_bt(const u16* __restrict__ Amat,
                                                 const u16* __restrict__ Bt,
                                                 void* __restrict__ Cout,
                                                 int M, int N, int K) {
    __shared__ __align__(16) u16 As[128 * 64];
    __shared__ __align__(16) u16 Bs[128 * 64];
    const int t = threadIdx.x;
    const int lane = t & 63, wave = t >> 6;
    const int m16 = lane & 15, qd = lane >> 4;
    const int wm = (wave >> 1) * 64, wn = (wave & 1) * 64;
    const size_t m0 = (size_t)blockIdx.y * 128, n0 = (size_t)blockIdx.x * 128;
    const int srow = lane >> 3;
    const int schunk = (lane & 7) ^ srow;

    f32x4 acc[4][4] = {};

    for (int k0 = 0; k0 < K; k0 += 64) {
#pragma unroll
        for (int j = 0; j < 4; ++j) {
            int rbase = j * 32 + wave * 8;
            int r = rbase + srow;
            gl2lds16(Amat + (m0 + r) * (size_t)K + k0 + schunk * 8, &As[rbase * 64]);
            gl2lds16(Bt   + (n0 + r) * (size_t)K + k0 + schunk * 8, &Bs[rbase * 64]);
        }
        __syncthreads();
#pragma unroll
        for (int kh = 0; kh < 2; ++kh) {
            s16x8 af[4], bf[4];
#pragma unroll
            for (int i = 0; i < 4; ++i) {
                int ra = wm + i * 16 + m16;
                int pa = (kh * 4 + qd) ^ (ra & 7);
                af[i] = *reinterpret_cast<const s16x8*>(&As[ra * 64 + pa * 8]);
                int rb = wn + i * 16 + m16;
                int pb = (kh * 4 + qd) ^ (rb & 7);
                bf[i] = *reinterpret_cast<const s16x8*>(&Bs[rb * 64 + pb * 8]);
            }
#pragma unroll
            for (int i = 0; i < 4; ++i)
#pragma unroll
                for (int jj = 0; jj < 4; ++jj)
                    acc[i][jj] = __builtin_amdgcn_mfma_f32_16x16x32_bf16(af[i], bf[jj], acc[i][jj], 0, 0, 0);
        }
        __syncthreads();
    }
    if (ROPE && n0 < 4096) {
        float invf[4];
#pragma unroll
        for (int j = 0; j < 4; ++j) {
            int pi = ((int)(wn + j * 16 + m16) & 127) >> 1;
            invf[j] = __expf(-0.14391156831f * (float)pi);
        }
#pragma unroll
        for (int i = 0; i < 4; ++i)
#pragma unroll
            for (int j = 0; j < 4; ++j)
#pragma unroll
                for (int r = 0; r < 4; ++r) {
                    float v = acc[i][j][r];
                    float p = __shfl_xor(v, 1);
                    size_t row = m0 + wm + i * 16 + qd * 4 + r;
                    float f = (float)(int)(row & 2047) * invf[j];
                    float sn, cs;
                    __sincosf(f, &sn, &cs);
                    float res = (m16 & 1) ? fmaf(p, sn, v * cs) : fmaf(v, cs, -p * sn);
                    size_t col = n0 + wn + j * 16 + m16;
                    ((u16*)Cout)[row * N + col] = f32_to_bf16_rne(res);
                }
    } else {
#pragma unroll
        for (int i = 0; i < 4; ++i)
#pragma unroll
            for (int j = 0; j < 4; ++j)
#pragma unroll
                for (int r = 0; r < 4; ++r) {
                    size_t row = m0 + wm + i * 16 + qd * 4 + r;
                    size_t col = n0 + wn + j * 16 + m16;
                    if (BF16OUT)
                        ((u16*)Cout)[row * N + col] = f32_to_bf16_rne(acc[i][j][r]);
                    else
                        ((float*)Cout)[row * N + col] = acc[i][j][r];
                }
    }
}

// ---------- 3b) 256x256-tile 8-phase GEMM (T2+T3+T4+T5) for QKV proj ----------
// v2: (a) 1 half-tile staged PER PHASE (m201 discipline) so every half of
// tile t+1 is in flight 4-7 phases before use:
//   P1(t): A1(t+1)->p^1   [p^1 A-reads done end-P3(t-1)]
//   P2(t): B1(t+1)->p^1   [p^1 B-reads done end-P2(t-1)]
//   P3(t): B0(t+2)->p     [p   B-reads done end-P2(t)]
//   P4(t): A0(t+2)->p     [p   A-reads done end-P3(t)]
// vmcnt(4) at P4 only: ledger = 12 outstanding, 8 oldest = all of t+1,
// 4 (half of t+2) stay in flight across the barrier — never drains.
// (b) chunked XCD swizzle: 8 XCDs = 4x2 chunks of 6(bx)x8(by) — per-XCD
// working set 6 B-panels + 8 A-panels instead of 24 B-panels.
template<bool BF16OUT, bool ROPE>
__global__ __launch_bounds__(512) void k_gemm256(const u16* __restrict__ Amat,
                                                 const u16* __restrict__ Bt,
                                                 void* __restrict__ Cout,
                                                 int M, int N, int K) {
    __shared__ __align__(16) u16 As[2][256 * 64];
    __shared__ __align__(16) u16 Bs[2][256 * 64];
    const int t = threadIdx.x;
    const int lane = t & 63, wave = t >> 6;
    const int m16 = lane & 15, qd = lane >> 4;
    const int wr = wave >> 2, wc = wave & 3;          // 2 x 4 wave grid
    const int srow = lane >> 3;                        // 0..7
    const int sch = (lane & 7) ^ srow;                 // pre-swizzled global k-chunk

    // chunked XCD-aware swizzle (grid 24x16; fallback = identity)
    int bx, by;
    if (gridDim.x == 24 && gridDim.y == 16) {
        int orig = blockIdx.y * gridDim.x + blockIdx.x;
        int xcd = orig & 7, loc = orig >> 3;           // loc 0..47
        int cx = xcd & 3, cy = xcd >> 2;               // 4 x-chunks, 2 y-chunks
        int lx = loc % 6, ly = loc / 6;                // 6x8 chunk
        bx = cx * 6 + lx; by = cy * 8 + ly;
    } else {
        bx = blockIdx.x; by = blockIdx.y;
    }
    const size_t m0 = (size_t)by * 256, n0 = (size_t)bx * 256;

    const u16* Ab = Amat + m0 * (size_t)K;
    const u16* Bb = Bt + n0 * (size_t)K;
    const int NT = K >> 6;

    // stage one 128-row half (2 x gl2lds/thread; LDS dest linear, src pre-swizzled)
    auto stageA = [&](int p, int h, int k0) {
        int rb0 = h * 128 + wave * 8;
        gl2lds16(Ab + (size_t)(rb0 + srow) * K + k0 + sch * 8, &As[p][rb0 * 64]);
        int rb1 = rb0 + 64;
        gl2lds16(Ab + (size_t)(rb1 + srow) * K + k0 + sch * 8, &As[p][rb1 * 64]);
    };
    auto stageB = [&](int p, int h, int k0) {
        int rb0 = h * 128 + wave * 8;
        gl2lds16(Bb + (size_t)(rb0 + srow) * K + k0 + sch * 8, &Bs[p][rb0 * 64]);
        int rb1 = rb0 + 64;
        gl2lds16(Bb + (size_t)(rb1 + srow) * K + k0 + sch * 8, &Bs[p][rb1 * 64]);
    };

    f32x4 acc[8][4] = {};
    s16x8 af[4][2], bq0[2][2], bq1[2][2];

    // ---- prologue: tile0 complete + B0(1) + A0(1); counted drain ----
    stageB(0, 0, 0); stageA(0, 0, 0); stageA(0, 1, 0); stageB(0, 1, 0);
    if (NT > 1) {
        stageB(1, 0, 64); stageA(1, 0, 64);
        asm volatile("s_waitcnt vmcnt(4)" ::: "memory");   // tile0's 8 loads landed
    } else {
        asm volatile("s_waitcnt vmcnt(0)" ::: "memory");
    }
    __builtin_amdgcn_s_barrier();

    for (int kt = 0; kt < NT; ++kt) {
        const int p = kt & 1;
        const int rowA = wr * 128;

        // ===== P1: read A[m0-half] + B[n0-half]; stage A1(kt+1)->p^1; MFMA m0 x n0 =====
#pragma unroll
        for (int i = 0; i < 4; ++i) {
            int ra = rowA + i * 16 + m16;
            af[i][0] = *reinterpret_cast<const s16x8*>(&As[p][ra * 64 + ((qd)     ^ (ra & 7)) * 8]);
            af[i][1] = *reinterpret_cast<const s16x8*>(&As[p][ra * 64 + ((4 + qd) ^ (ra & 7)) * 8]);
        }
#pragma unroll
        for (int j = 0; j < 2; ++j) {
            int rb = wc * 64 + j * 16 + m16;
            bq0[j][0] = *reinterpret_cast<const s16x8*>(&Bs[p][rb * 64 + ((qd)     ^ (rb & 7)) * 8]);
            bq0[j][1] = *reinterpret_cast<const s16x8*>(&Bs[p][rb * 64 + ((4 + qd) ^ (rb & 7)) * 8]);
        }
        if (kt + 1 < NT) stageA(p ^ 1, 1, (kt + 1) << 6);
        __builtin_amdgcn_s_barrier();
        asm volatile("s_waitcnt lgkmcnt(0)" ::: "memory");
        __builtin_amdgcn_s_setprio(1);
#pragma unroll
        for (int i = 0; i < 4; ++i)
#pragma unroll
            for (int j = 0; j < 2; ++j) {
                acc[i][j] = __builtin_amdgcn_mfma_f32_16x16x32_bf16(af[i][0], bq0[j][0], acc[i][j], 0, 0, 0);
                acc[i][j] = __builtin_amdgcn_mfma_f32_16x16x32_bf16(af[i][1], bq0[j][1], acc[i][j], 0, 0, 0);
            }
        __builtin_amdgcn_s_setprio(0);
        __builtin_amdgcn_s_barrier();

        // ===== P2: read B[n1-half]; stage B1(kt+1)->p^1; MFMA m0 x n1 =====
#pragma unroll
        for (int j = 0; j < 2; ++j) {
            int rb = wc * 64 + 32 + j * 16 + m16;
            bq1[j][0] = *reinterpret_cast<const s16x8*>(&Bs[p][rb * 64 + ((qd)     ^ (rb & 7)) * 8]);
            bq1[j][1] = *reinterpret_cast<const s16x8*>(&Bs[p][rb * 64 + ((4 + qd) ^ (rb & 7)) * 8]);
        }
        if (kt + 1 < NT) stageB(p ^ 1, 1, (kt + 1) << 6);
        __builtin_amdgcn_s_barrier();
        asm volatile("s_waitcnt lgkmcnt(0)" ::: "memory");
        __builtin_amdgcn_s_setprio(1);
#pragma unroll
        for (int i = 0; i < 4; ++i)
#pragma unroll
            for (int j = 0; j < 2; ++j) {
                acc[i][2 + j] = __builtin_amdgcn_mfma_f32_16x16x32_bf16(af[i][0], bq1[j][0], acc[i][2 + j], 0, 0, 0);
                acc[i][2 + j] = __builtin_amdgcn_mfma_f32_16x16x32_bf16(af[i][1], bq1[j][1], acc[i][2 + j], 0, 0, 0);
            }
        __builtin_amdgcn_s_setprio(0);
        __builtin_amdgcn_s_barrier();

        // ===== P3: read A[m1-half]; stage B0(kt+2)->p; MFMA m1 x n1 =====
#pragma unroll
        for (int i = 0; i < 4; ++i) {
            int ra = rowA + 64 + i * 16 + m16;
            af[i][0] = *reinterpret_cast<const s16x8*>(&As[p][ra * 64 + ((qd)     ^ (ra & 7)) * 8]);
            af[i][1] = *reinterpret_cast<const s16x8*>(&As[p][ra * 64 + ((4 + qd) ^ (ra & 7)) * 8]);
        }
        if (kt + 2 < NT) stageB(p, 0, (kt + 2) << 6);
        __builtin_amdgcn_s_barrier();
        asm volatile("s_waitcnt lgkmcnt(0)" ::: "memory");
        __builtin_amdgcn_s_setprio(1);
#pragma unroll
        for (int i = 0; i < 4; ++i)
#pragma unroll
            for (int j = 0; j < 2; ++j) {
                acc[4 + i][2 + j] = __builtin_amdgcn_mfma_f32_16x16x32_bf16(af[i][0], bq1[j][0], acc[4 + i][2 + j], 0, 0, 0);
                acc[4 + i][2 + j] = __builtin_amdgcn_mfma_f32_16x16x32_bf16(af[i][1], bq1[j][1], acc[4 + i][2 + j], 0, 0, 0);
            }
        __builtin_amdgcn_s_setprio(0);
        __builtin_amdgcn_s_barrier();

        // ===== P4: stage A0(kt+2)->p; counted vmcnt (tile kt+1 landed); MFMA m1 x n0 =====
        if (kt + 2 < NT) {
            stageA(p, 0, (kt + 2) << 6);
            asm volatile("s_waitcnt vmcnt(4)" ::: "memory");
        } else {
            asm volatile("s_waitcnt vmcnt(0)" ::: "memory");
        }
        __builtin_amdgcn_s_barrier();
        __builtin_amdgcn_s_setprio(1);
#pragma unroll
        for (int i = 0; i < 4; ++i)
#pragma unroll
            for (int j = 0; j < 2; ++j) {
                acc[4 + i][j] = __builtin_amdgcn_mfma_f32_16x16x32_bf16(af[i][0], bq0[j][0], acc[4 + i][j], 0, 0, 0);
                acc[4 + i][j] = __builtin_amdgcn_mfma_f32_16x16x32_bf16(af[i][1], bq0[j][1], acc[4 + i][j], 0, 0, 0);
            }
        __builtin_amdgcn_s_setprio(0);
        __builtin_amdgcn_s_barrier();
    }

    // ---- epilogue ----
    if (ROPE && n0 < 4096) {
        float invf[4];
#pragma unroll
        for (int j = 0; j < 4; ++j) {
            int pi = ((int)(wc * 64 + j * 16 + m16) & 127) >> 1;
            invf[j] = __expf(-0.14391156831f * (float)pi);
        }
#pragma unroll
        for (int i = 0; i < 8; ++i)
#pragma unroll
            for (int j = 0; j < 4; ++j)
#pragma unroll
                for (int r = 0; r < 4; ++r) {
                    float v = acc[i][j][r];
                    float pv = __shfl_xor(v, 1);
                    size_t row = m0 + wr * 128 + i * 16 + qd * 4 + r;
                    float f = (float)(int)(row & 2047) * invf[j];
                    float sn, cs;
                    __sincosf(f, &sn, &cs);
                    float res = (m16 & 1) ? fmaf(pv, sn, v * cs) : fmaf(v, cs, -pv * sn);
                    size_t col = n0 + wc * 64 + j * 16 + m16;
                    ((u16*)Cout)[row * N + col] = f32_to_bf16_rne(res);
                }
    } else {
#pragma unroll
        for (int i = 0; i < 8; ++i)
#pragma unroll
            for (int j = 0; j < 4; ++j)
#pragma unroll
                for (int r = 0; r < 4; ++r) {
                    size_t row = m0 + wr * 128 + i * 16 + qd * 4 + r;
                    size_t col = n0 + wc * 64 + j * 16 + m16;
                    if (BF16OUT)
                        ((u16*)Cout)[row * N + col] = f32_to_bf16_rne(acc[i][j][r]);
                    else
                        ((float*)Cout)[row * N + col] = acc[i][j][r];
                }
    }
}

// ---------- 4) V -> V^T ----------
__global__ __launch_bounds__(256) void k_transpose_v(const u16* __restrict__ qkv,
                                                     u16* __restrict__ vt) {
    __shared__ u16 TT[128 * 130];
    const int t = threadIdx.x;
    const int st = blockIdx.x;
    const int bh = blockIdx.y;
    const int b = bh >> 4, h = bh & 15;
    const u16* src = qkv + (size_t)b * 2048 * 6144 + 4096 + (size_t)h * 128;
    const int tr = t >> 4, tc = t & 15;
    s16x8 v[8];
#pragma unroll
    for (int u = 0; u < 8; ++u) {
        int s = u * 16 + tr;
        v[u] = *reinterpret_cast<const s16x8*>(src + (size_t)(st * 128 + s) * 6144 + tc * 8);
    }
#pragma unroll
    for (int u = 0; u < 8; ++u) {
        int s = u * 16 + tr;
#pragma unroll
        for (int e = 0; e < 8; ++e)
            TT[(tc * 8 + e) * 130 + s] = (u16)v[u][e];
    }
    __syncthreads();
    u16* dst = vt + (size_t)bh * 128 * 2048 + st * 128;
#pragma unroll
    for (int u = 0; u < 8; ++u) {
        int d = u * 16 + tr;
        int s0 = tc * 8;
        s16x8 o;
#pragma unroll
        for (int e = 0; e < 8; ++e) o[e] = (short)TT[d * 130 + s0 + e];
        *reinterpret_cast<s16x8*>(dst + (size_t)d * 2048 + s0) = o;
    }
}

// ---------- 5) flash attention (unchanged — protected win) ----------
__global__ __launch_bounds__(512, 4) void k_flash(const u16* __restrict__ qkv,
                                                  const u16* __restrict__ vt,
                                                  u16* __restrict__ out) {
    __shared__ __align__(16) u16 KS[128 * 136];
    __shared__ __align__(16) u16 VS[128 * 136];
    const int t = threadIdx.x, lane = t & 63, wave = t >> 6;
    const int m16 = lane & 15, qd = lane >> 4;
    const int bh = blockIdx.y, b = bh >> 4, h = bh & 15;
    const int q0 = blockIdx.x * 128;
    const u16* Qg = qkv + (size_t)b * 2048 * 6144 + (size_t)h * 128;
    const u16* Kg = Qg + 2048;
    const u16* Vtg = vt + (size_t)bh * 128 * 2048;
    const float C2 = 0.12751743f;

    int srow[4], scol[4], pi0[4];
#pragma unroll
    for (int ci = 0; ci < 4; ++ci) {
        int idx = ci * 512 + t;
        int row = idx >> 4, c = idx & 15;
        srow[ci] = row;
        scol[ci] = c * 8;
        pi0[ci] = 32 * (c >> 2) + 16 * (c & 1) + 4 * ((c >> 1) & 1);
    }

    s16x8 qf[4];
#pragma unroll
    for (int kc = 0; kc < 4; ++kc)
        qf[kc] = *reinterpret_cast<const s16x8*>(
            Qg + (size_t)(q0 + wave * 16 + m16) * 6144 + kc * 32 + qd * 8);

    f32x4 accO[8] = {};
    float mrow = -1e30f, lrow = 0.f;

    for (int kt = 0; kt < 16; ++kt) {
        const int s0 = kt * 128;
        s16x8 kreg[4], vreg[4];
#pragma unroll
        for (int ci = 0; ci < 4; ++ci) {
            kreg[ci] = *reinterpret_cast<const s16x8*>(
                Kg + (size_t)(s0 + srow[ci]) * 6144 + scol[ci]);
            vreg[ci] = *reinterpret_cast<const s16x8*>(
                Vtg + (size_t)srow[ci] * 2048 + s0 + scol[ci]);
        }
        __syncthreads();
#pragma unroll
        for (int ci = 0; ci < 4; ++ci) {
            *reinterpret_cast<s16x8*>(&KS[srow[ci] * 136 + scol[ci]]) = kreg[ci];
            s16x4 lo = __builtin_shufflevector(vreg[ci], vreg[ci], 0, 1, 2, 3);
            s16x4 hi = __builtin_shufflevector(vreg[ci], vreg[ci], 4, 5, 6, 7);
            *reinterpret_cast<s16x4*>(&VS[srow[ci] * 136 + pi0[ci]]) = lo;
            *reinterpret_cast<s16x4*>(&VS[srow[ci] * 136 + pi0[ci] + 8]) = hi;
        }
        __syncthreads();

        f32x4 accS[8] = {};
#pragma unroll
        for (int kc = 0; kc < 4; ++kc)
#pragma unroll
            for (int nj = 0; nj < 8; ++nj) {
                s16x8 kf = *reinterpret_cast<const s16x8*>(
                    &KS[(nj * 16 + m16) * 136 + (kc * 4 + qd) * 8]);
                accS[nj] = __builtin_amdgcn_mfma_f32_16x16x32_bf16(kf, qf[kc], accS[nj], 0, 0, 0);
            }

        float mx = accS[0][0];
#pragma unroll
        for (int nj = 0; nj < 8; ++nj)
#pragma unroll
            for (int r = 0; r < 4; ++r) mx = fmaxf(mx, accS[nj][r]);
        mx *= C2;
        mx = fmaxf(mx, __shfl_xor(mx, 16));
        mx = fmaxf(mx, __shfl_xor(mx, 32));
        float mn = fmaxf(mrow, mx);
        float alpha = __builtin_amdgcn_exp2f(mrow - mn);
        mrow = mn;
        float ls = 0.f;
        s16x4 pk[8];
#pragma unroll
        for (int nj = 0; nj < 8; ++nj) {
            float p0 = __builtin_amdgcn_exp2f(fmaf(accS[nj][0], C2, -mn));
            float p1 = __builtin_amdgcn_exp2f(fmaf(accS[nj][1], C2, -mn));
            float p2 = __builtin_amdgcn_exp2f(fmaf(accS[nj][2], C2, -mn));
            float p3 = __builtin_amdgcn_exp2f(fmaf(accS[nj][3], C2, -mn));
            ls += (p0 + p1) + (p2 + p3);
            u32 lo = pack_bf16_rhu(p0, p1);
            u32 hi = pack_bf16_rhu(p2, p3);
            uint2 pr = make_uint2(lo, hi);
            pk[nj] = __builtin_bit_cast(s16x4, pr);
        }
        ls += __shfl_xor(ls, 16);
        ls += __shfl_xor(ls, 32);
        lrow = lrow * alpha + ls;
        float aO[4];
#pragma unroll
        for (int r = 0; r < 4; ++r) aO[r] = __shfl(alpha, qd * 4 + r);
#pragma unroll
        for (int dj = 0; dj < 8; ++dj)
#pragma unroll
            for (int r = 0; r < 4; ++r) accO[dj][r] *= aO[r];

#pragma unroll
        for (int kb = 0; kb < 4; ++kb) {
            s16x8 af = __builtin_shufflevector(pk[2 * kb], pk[2 * kb + 1],
                                               0, 1, 2, 3, 4, 5, 6, 7);
#pragma unroll
            for (int dj = 0; dj < 8; ++dj) {
                s16x8 vf = *reinterpret_cast<const s16x8*>(
                    &VS[(dj * 16 + m16) * 136 + kb * 32 + qd * 8]);
                accO[dj] = __builtin_amdgcn_mfma_f32_16x16x32_bf16(af, vf, accO[dj], 0, 0, 0);
            }
        }
    }
    float invl = 1.0f / lrow;
    float iv[4];
#pragma unroll
    for (int r = 0; r < 4; ++r) iv[r] = __shfl(invl, qd * 4 + r);
#pragma unroll
    for (int r = 0; r < 4; ++r) {
        size_t row = (size_t)b * 2048 + q0 + wave * 16 + qd * 4 + r;
#pragma unroll
        for (int dj = 0; dj < 8; ++dj)
            out[row * 2048 + h * 128 + dj * 16 + m16] =
                f32_to_bf16_rne(accO[dj][r] * iv[r]);
    }
}

// ---------- launch ----------
extern "C" void kernel_launch(void* const* d_in, const int* in_sizes, int n_in,
                              void* d_out, int out_size, void* d_ws, size_t ws_size,
                              hipStream_t stream) {
    const float* x     = (const float*)d_in[0];
    const float* W_qkv = (const float*)d_in[1];
    const float* W_out = (const float*)d_in[2];
    float* out = (float*)d_out;

    char* ws = (char*)d_ws;
    u16* xb   = (u16*)(ws);
    u16* Wqt  = (u16*)(ws + (16u << 20));
    u16* Wot  = (u16*)(ws + (40u << 20));
    u16* qkvb = (u16*)(ws + (48u << 20));
    u16* attn = (u16*)(ws + (96u << 20));
    u16* vtg  = (u16*)(ws + (112u << 20));

    k_cast<<<4096, 256, 0, stream>>>(x, xb);
    k_transpose_cast<<<dim3(96, 16), 256, 0, stream>>>(W_qkv, Wqt, 2048, 6144);
    k_transpose_cast<<<dim3(32, 16), 256, 0, stream>>>(W_out, Wot, 2048, 2048);
    k_gemm256<true, true><<<dim3(24, 16), 512, 0, stream>>>(xb, Wqt, qkvb, 4096, 6144, 2048);
    k_transpose_v<<<dim3(16, 32), 256, 0, stream>>>(qkvb, vtg);
    k_flash<<<dim3(16, 32), 512, 0, stream>>>(qkvb, vtg, attn);
    k_gemm_bt<false, false><<<dim3(16, 32), 256, 0, stream>>>(attn, Wot, out, 4096, 2048, 2048);
}

// Round 3
// 408.793 us; speedup vs baseline: 1.0156x; 1.0156x over previous
//
#include <hip/hip_runtime.h>
#include <math.h>

typedef float  f32x4 __attribute__((ext_vector_type(4)));
typedef short  s16x8 __attribute__((ext_vector_type(8)));
typedef short  s16x4 __attribute__((ext_vector_type(4)));
typedef unsigned short u16;
typedef unsigned int u32;

// ---------- bf16 helpers ----------
static __device__ __forceinline__ u16 f32_to_bf16_rne(float f) {
    u32 u = __builtin_bit_cast(u32, f);
    u32 r = u + 0x7fffu + ((u >> 16) & 1u);
    return (u16)(r >> 16);
}
static __device__ __forceinline__ u32 pack_bf16_rhu(float a, float b) {
    u32 ua = __builtin_bit_cast(u32, a);
    u32 ub = __builtin_bit_cast(u32, b);
    return ((ua + 0x8000u) >> 16) | ((ub + 0x8000u) & 0xffff0000u);
}
static __device__ __forceinline__ float bf16_to_f32(u16 h) {
    return __builtin_bit_cast(float, (u32)h << 16);
}

// async global->LDS 16B (lane-contiguous LDS dest ONLY; source is per-lane)
static __device__ __forceinline__ void gl2lds16(const void* g, void* l) {
    __builtin_amdgcn_global_load_lds(
        (const __attribute__((address_space(1))) u32*)g,
        (__attribute__((address_space(3))) u32*)l, 16, 0, 0);
}

// ---------- 1) cast fp32 -> bf16 ----------
__global__ __launch_bounds__(256) void k_cast(const float* __restrict__ in,
                                              u16* __restrict__ out) {
    int i = (blockIdx.x * 256 + threadIdx.x) * 8;
    float4 a = *reinterpret_cast<const float4*>(in + i);
    float4 b = *reinterpret_cast<const float4*>(in + i + 4);
    s16x8 o;
    o[0] = (short)f32_to_bf16_rne(a.x); o[1] = (short)f32_to_bf16_rne(a.y);
    o[2] = (short)f32_to_bf16_rne(a.z); o[3] = (short)f32_to_bf16_rne(a.w);
    o[4] = (short)f32_to_bf16_rne(b.x); o[5] = (short)f32_to_bf16_rne(b.y);
    o[6] = (short)f32_to_bf16_rne(b.z); o[7] = (short)f32_to_bf16_rne(b.w);
    *reinterpret_cast<s16x8*>(out + i) = o;
}

// ---------- 2) transpose + cast ----------
__global__ __launch_bounds__(256) void k_transpose_cast(const float* __restrict__ in,
                                                        u16* __restrict__ out,
                                                        int R, int C) {
    __shared__ float TT[64 * 130];
    const int t = threadIdx.x;
    const int ct = blockIdx.x, rt = blockIdx.y;
    const int tr = t >> 4;
    const int tc = t & 15;
    float4 v[8];
#pragma unroll
    for (int u = 0; u < 8; ++u) {
        int r = u * 16 + tr;
        v[u] = *reinterpret_cast<const float4*>(in + (size_t)(rt * 128 + r) * C + ct * 64 + tc * 4);
    }
#pragma unroll
    for (int u = 0; u < 8; ++u) {
        int r = u * 16 + tr;
        TT[(tc * 4 + 0) * 130 + r] = v[u].x;
        TT[(tc * 4 + 1) * 130 + r] = v[u].y;
        TT[(tc * 4 + 2) * 130 + r] = v[u].z;
        TT[(tc * 4 + 3) * 130 + r] = v[u].w;
    }
    __syncthreads();
#pragma unroll
    for (int u = 0; u < 4; ++u) {
        int oc = u * 16 + tr;
        int r0 = tc * 8;
        s16x8 o;
#pragma unroll
        for (int e = 0; e < 8; ++e)
            o[e] = (short)f32_to_bf16_rne(TT[oc * 130 + r0 + e]);
        *reinterpret_cast<s16x8*>(out + (size_t)(ct * 64 + oc) * R + rt * 128 + r0) = o;
    }
}

// ---------- 3a) m97-style 128x128 GEMM (kept for out-projection) ----------
template<bool BF16OUT, bool ROPE>
__global__ __launch_bounds__(256) void k_gemm_bt(const u16* __restrict__ Amat,
                                                 const u16* __restrict__ Bt,
                                                 void* __restrict__ Cout,
                                                 int M, int N, int K) {
    __shared__ __align__(16) u16 As[128 * 64];
    __shared__ __align__(16) u16 Bs[128 * 64];
    const int t = threadIdx.x;
    const int lane = t & 63, wave = t >> 6;
    const int m16 = lane & 15, qd = lane >> 4;
    const int wm = (wave >> 1) * 64, wn = (wave & 1) * 64;
    const size_t m0 = (size_t)blockIdx.y * 128, n0 = (size_t)blockIdx.x * 128;
    const int srow = lane >> 3;
    const int schunk = (lane & 7) ^ srow;

    f32x4 acc[4][4] = {};

    for (int k0 = 0; k0 < K; k0 += 64) {
#pragma unroll
        for (int j = 0; j < 4; ++j) {
            int rbase = j * 32 + wave * 8;
            int r = rbase + srow;
            gl2lds16(Amat + (m0 + r) * (size_t)K + k0 + schunk * 8, &As[rbase * 64]);
            gl2lds16(Bt   + (n0 + r) * (size_t)K + k0 + schunk * 8, &Bs[rbase * 64]);
        }
        __syncthreads();
#pragma unroll
        for (int kh = 0; kh < 2; ++kh) {
            s16x8 af[4], bf[4];
#pragma unroll
            for (int i = 0; i < 4; ++i) {
                int ra = wm + i * 16 + m16;
                int pa = (kh * 4 + qd) ^ (ra & 7);
                af[i] = *reinterpret_cast<const s16x8*>(&As[ra * 64 + pa * 8]);
                int rb = wn + i * 16 + m16;
                int pb = (kh * 4 + qd) ^ (rb & 7);
                bf[i] = *reinterpret_cast<const s16x8*>(&Bs[rb * 64 + pb * 8]);
            }
#pragma unroll
            for (int i = 0; i < 4; ++i)
#pragma unroll
                for (int jj = 0; jj < 4; ++jj)
                    acc[i][jj] = __builtin_amdgcn_mfma_f32_16x16x32_bf16(af[i], bf[jj], acc[i][jj], 0, 0, 0);
        }
        __syncthreads();
    }
    if (ROPE && n0 < 4096) {
        float invf[4];
#pragma unroll
        for (int j = 0; j < 4; ++j) {
            int pi = ((int)(wn + j * 16 + m16) & 127) >> 1;
            invf[j] = __expf(-0.14391156831f * (float)pi);
        }
#pragma unroll
        for (int i = 0; i < 4; ++i)
#pragma unroll
            for (int j = 0; j < 4; ++j)
#pragma unroll
                for (int r = 0; r < 4; ++r) {
                    float v = acc[i][j][r];
                    float p = __shfl_xor(v, 1);
                    size_t row = m0 + wm + i * 16 + qd * 4 + r;
                    float f = (float)(int)(row & 2047) * invf[j];
                    float sn, cs;
                    __sincosf(f, &sn, &cs);
                    float res = (m16 & 1) ? fmaf(p, sn, v * cs) : fmaf(v, cs, -p * sn);
                    size_t col = n0 + wn + j * 16 + m16;
                    ((u16*)Cout)[row * N + col] = f32_to_bf16_rne(res);
                }
    } else {
#pragma unroll
        for (int i = 0; i < 4; ++i)
#pragma unroll
            for (int j = 0; j < 4; ++j)
#pragma unroll
                for (int r = 0; r < 4; ++r) {
                    size_t row = m0 + wm + i * 16 + qd * 4 + r;
                    size_t col = n0 + wn + j * 16 + m16;
                    if (BF16OUT)
                        ((u16*)Cout)[row * N + col] = f32_to_bf16_rne(acc[i][j][r]);
                    else
                        ((float*)Cout)[row * N + col] = acc[i][j][r];
                }
    }
}

// ---------- 3b) 256x256-tile GEMM, kh-split 4-phase schedule (v3) ----------
// Phase structure per K-tile (the fix): phases = {m0*kh0, m0*kh1, m1*kh0, m1*kh1}.
// Each phase: 16 FULLY INDEPENDENT MFMAs (every acc[i][j] touched once per
// phase) — no back-to-back dependent MFMA pairs. Balanced ds_reads per phase:
// 8,8,4,4 (bq[4][2] held in registers across the K-tile; af reloaded).
// Staging (1 half-tile/phase, re-derived for new read lifetimes):
//   P1(t): A0(t+1)->p^1   P2(t): A1(t+1)->p^1   (A(p^1) reads ended at t-1)
//   P3(t): B0(t+2)->p     P4(t): B1(t+2)->p     (B(p) reads ended at P2(t))
// vmcnt(4) at P4 only: 12 outstanding, 8 oldest = all of tile t+1 (B01 then
// A01), 4 newest (B(t+2)) stay in flight — never drains in the main loop.
template<bool BF16OUT, bool ROPE>
__global__ __launch_bounds__(512) void k_gemm256(const u16* __restrict__ Amat,
                                                 const u16* __restrict__ Bt,
                                                 void* __restrict__ Cout,
                                                 int M, int N, int K) {
    __shared__ __align__(16) u16 As[2][256 * 64];
    __shared__ __align__(16) u16 Bs[2][256 * 64];
    const int t = threadIdx.x;
    const int lane = t & 63, wave = t >> 6;
    const int m16 = lane & 15, qd = lane >> 4;
    const int wr = wave >> 2, wc = wave & 3;          // 2 x 4 wave grid
    const int srow = lane >> 3;                        // 0..7
    const int sch = (lane & 7) ^ srow;                 // pre-swizzled global k-chunk

    // chunked XCD-aware swizzle (grid 24x16; fallback = identity)
    int bx, by;
    if (gridDim.x == 24 && gridDim.y == 16) {
        int orig = blockIdx.y * gridDim.x + blockIdx.x;
        int xcd = orig & 7, loc = orig >> 3;           // loc 0..47
        int cx = xcd & 3, cy = xcd >> 2;               // 4 x-chunks, 2 y-chunks
        int lx = loc % 6, ly = loc / 6;                // 6x8 chunk
        bx = cx * 6 + lx; by = cy * 8 + ly;
    } else {
        bx = blockIdx.x; by = blockIdx.y;
    }
    const size_t m0 = (size_t)by * 256, n0 = (size_t)bx * 256;

    const u16* Ab = Amat + m0 * (size_t)K;
    const u16* Bb = Bt + n0 * (size_t)K;
    const int NT = K >> 6;

    auto stageA = [&](int p, int h, int k0) {
        int rb0 = h * 128 + wave * 8;
        gl2lds16(Ab + (size_t)(rb0 + srow) * K + k0 + sch * 8, &As[p][rb0 * 64]);
        int rb1 = rb0 + 64;
        gl2lds16(Ab + (size_t)(rb1 + srow) * K + k0 + sch * 8, &As[p][rb1 * 64]);
    };
    auto stageB = [&](int p, int h, int k0) {
        int rb0 = h * 128 + wave * 8;
        gl2lds16(Bb + (size_t)(rb0 + srow) * K + k0 + sch * 8, &Bs[p][rb0 * 64]);
        int rb1 = rb0 + 64;
        gl2lds16(Bb + (size_t)(rb1 + srow) * K + k0 + sch * 8, &Bs[p][rb1 * 64]);
    };

    f32x4 acc[8][4] = {};
    s16x8 af[4], bq[4][2];

    // ---- prologue: tile0 (A then B) + B(1); counted drain ----
    stageA(0, 0, 0); stageA(0, 1, 0);
    stageB(0, 0, 0); stageB(0, 1, 0);
    if (NT > 1) {
        stageB(1, 0, 64); stageB(1, 1, 64);
        asm volatile("s_waitcnt vmcnt(4)" ::: "memory");   // tile0's 8 loads landed
    } else {
        asm volatile("s_waitcnt vmcnt(0)" ::: "memory");
    }
    __builtin_amdgcn_s_barrier();

    for (int kt = 0; kt < NT; ++kt) {
        const int p = kt & 1;
        const int rowA = wr * 128;

        // ===== P1: read af(m0,kh0) + bq(*,kh0); stage A0(kt+1)->p^1; MFMA m0*kh0 =====
#pragma unroll
        for (int i = 0; i < 4; ++i) {
            int ra = rowA + i * 16 + m16;
            af[i] = *reinterpret_cast<const s16x8*>(&As[p][ra * 64 + ((qd) ^ (ra & 7)) * 8]);
        }
#pragma unroll
        for (int j = 0; j < 4; ++j) {
            int rb = wc * 64 + j * 16 + m16;
            bq[j][0] = *reinterpret_cast<const s16x8*>(&Bs[p][rb * 64 + ((qd) ^ (rb & 7)) * 8]);
        }
        if (kt + 1 < NT) stageA(p ^ 1, 0, (kt + 1) << 6);
        __builtin_amdgcn_s_barrier();
        asm volatile("s_waitcnt lgkmcnt(0)" ::: "memory");
        __builtin_amdgcn_s_setprio(1);
#pragma unroll
        for (int i = 0; i < 4; ++i)
#pragma unroll
            for (int j = 0; j < 4; ++j)
                acc[i][j] = __builtin_amdgcn_mfma_f32_16x16x32_bf16(af[i], bq[j][0], acc[i][j], 0, 0, 0);
        __builtin_amdgcn_s_setprio(0);
        __builtin_amdgcn_s_barrier();

        // ===== P2: read af(m0,kh1) + bq(*,kh1); stage A1(kt+1)->p^1; MFMA m0*kh1 =====
#pragma unroll
        for (int i = 0; i < 4; ++i) {
            int ra = rowA + i * 16 + m16;
            af[i] = *reinterpret_cast<const s16x8*>(&As[p][ra * 64 + ((4 + qd) ^ (ra & 7)) * 8]);
        }
#pragma unroll
        for (int j = 0; j < 4; ++j) {
            int rb = wc * 64 + j * 16 + m16;
            bq[j][1] = *reinterpret_cast<const s16x8*>(&Bs[p][rb * 64 + ((4 + qd) ^ (rb & 7)) * 8]);
        }
        if (kt + 1 < NT) stageA(p ^ 1, 1, (kt + 1) << 6);
        __builtin_amdgcn_s_barrier();
        asm volatile("s_waitcnt lgkmcnt(0)" ::: "memory");
        __builtin_amdgcn_s_setprio(1);
#pragma unroll
        for (int i = 0; i < 4; ++i)
#pragma unroll
            for (int j = 0; j < 4; ++j)
                acc[i][j] = __builtin_amdgcn_mfma_f32_16x16x32_bf16(af[i], bq[j][1], acc[i][j], 0, 0, 0);
        __builtin_amdgcn_s_setprio(0);
        __builtin_amdgcn_s_barrier();

        // ===== P3: read af(m1,kh0); stage B0(kt+2)->p; MFMA m1*kh0 =====
#pragma unroll
        for (int i = 0; i < 4; ++i) {
            int ra = rowA + 64 + i * 16 + m16;
            af[i] = *reinterpret_cast<const s16x8*>(&As[p][ra * 64 + ((qd) ^ (ra & 7)) * 8]);
        }
        if (kt + 2 < NT) stageB(p, 0, (kt + 2) << 6);
        __builtin_amdgcn_s_barrier();
        asm volatile("s_waitcnt lgkmcnt(0)" ::: "memory");
        __builtin_amdgcn_s_setprio(1);
#pragma unroll
        for (int i = 0; i < 4; ++i)
#pragma unroll
            for (int j = 0; j < 4; ++j)
                acc[4 + i][j] = __builtin_amdgcn_mfma_f32_16x16x32_bf16(af[i], bq[j][0], acc[4 + i][j], 0, 0, 0);
        __builtin_amdgcn_s_setprio(0);
        __builtin_amdgcn_s_barrier();

        // ===== P4: read af(m1,kh1); stage B1(kt+2)->p; counted vmcnt; MFMA m1*kh1 =====
#pragma unroll
        for (int i = 0; i < 4; ++i) {
            int ra = rowA + 64 + i * 16 + m16;
            af[i] = *reinterpret_cast<const s16x8*>(&As[p][ra * 64 + ((4 + qd) ^ (ra & 7)) * 8]);
        }
        if (kt + 2 < NT) {
            stageB(p, 1, (kt + 2) << 6);
            asm volatile("s_waitcnt vmcnt(4)" ::: "memory");
        } else {
            asm volatile("s_waitcnt vmcnt(0)" ::: "memory");
        }
        __builtin_amdgcn_s_barrier();
        asm volatile("s_waitcnt lgkmcnt(0)" ::: "memory");
        __builtin_amdgcn_s_setprio(1);
#pragma unroll
        for (int i = 0; i < 4; ++i)
#pragma unroll
            for (int j = 0; j < 4; ++j)
                acc[4 + i][j] = __builtin_amdgcn_mfma_f32_16x16x32_bf16(af[i], bq[j][1], acc[4 + i][j], 0, 0, 0);
        __builtin_amdgcn_s_setprio(0);
        __builtin_amdgcn_s_barrier();
    }

    // ---- epilogue ----
    if (ROPE && n0 < 4096) {
        float invf[4];
#pragma unroll
        for (int j = 0; j < 4; ++j) {
            int pi = ((int)(wc * 64 + j * 16 + m16) & 127) >> 1;
            invf[j] = __expf(-0.14391156831f * (float)pi);
        }
#pragma unroll
        for (int i = 0; i < 8; ++i)
#pragma unroll
            for (int j = 0; j < 4; ++j)
#pragma unroll
                for (int r = 0; r < 4; ++r) {
                    float v = acc[i][j][r];
                    float pv = __shfl_xor(v, 1);
                    size_t row = m0 + wr * 128 + i * 16 + qd * 4 + r;
                    float f = (float)(int)(row & 2047) * invf[j];
                    float sn, cs;
                    __sincosf(f, &sn, &cs);
                    float res = (m16 & 1) ? fmaf(pv, sn, v * cs) : fmaf(v, cs, -pv * sn);
                    size_t col = n0 + wc * 64 + j * 16 + m16;
                    ((u16*)Cout)[row * N + col] = f32_to_bf16_rne(res);
                }
    } else {
#pragma unroll
        for (int i = 0; i < 8; ++i)
#pragma unroll
            for (int j = 0; j < 4; ++j)
#pragma unroll
                for (int r = 0; r < 4; ++r) {
                    size_t row = m0 + wr * 128 + i * 16 + qd * 4 + r;
                    size_t col = n0 + wc * 64 + j * 16 + m16;
                    if (BF16OUT)
                        ((u16*)Cout)[row * N + col] = f32_to_bf16_rne(acc[i][j][r]);
                    else
                        ((float*)Cout)[row * N + col] = acc[i][j][r];
                }
    }
}

// ---------- 4) V -> V^T ----------
__global__ __launch_bounds__(256) void k_transpose_v(const u16* __restrict__ qkv,
                                                     u16* __restrict__ vt) {
    __shared__ u16 TT[128 * 130];
    const int t = threadIdx.x;
    const int st = blockIdx.x;
    const int bh = blockIdx.y;
    const int b = bh >> 4, h = bh & 15;
    const u16* src = qkv + (size_t)b * 2048 * 6144 + 4096 + (size_t)h * 128;
    const int tr = t >> 4, tc = t & 15;
    s16x8 v[8];
#pragma unroll
    for (int u = 0; u < 8; ++u) {
        int s = u * 16 + tr;
        v[u] = *reinterpret_cast<const s16x8*>(src + (size_t)(st * 128 + s) * 6144 + tc * 8);
    }
#pragma unroll
    for (int u = 0; u < 8; ++u) {
        int s = u * 16 + tr;
#pragma unroll
        for (int e = 0; e < 8; ++e)
            TT[(tc * 8 + e) * 130 + s] = (u16)v[u][e];
    }
    __syncthreads();
    u16* dst = vt + (size_t)bh * 128 * 2048 + st * 128;
#pragma unroll
    for (int u = 0; u < 8; ++u) {
        int d = u * 16 + tr;
        int s0 = tc * 8;
        s16x8 o;
#pragma unroll
        for (int e = 0; e < 8; ++e) o[e] = (short)TT[d * 130 + s0 + e];
        *reinterpret_cast<s16x8*>(dst + (size_t)d * 2048 + s0) = o;
    }
}

// ---------- 5) flash attention (unchanged — protected win) ----------
__global__ __launch_bounds__(512, 4) void k_flash(const u16* __restrict__ qkv,
                                                  const u16* __restrict__ vt,
                                                  u16* __restrict__ out) {
    __shared__ __align__(16) u16 KS[128 * 136];
    __shared__ __align__(16) u16 VS[128 * 136];
    const int t = threadIdx.x, lane = t & 63, wave = t >> 6;
    const int m16 = lane & 15, qd = lane >> 4;
    const int bh = blockIdx.y, b = bh >> 4, h = bh & 15;
    const int q0 = blockIdx.x * 128;
    const u16* Qg = qkv + (size_t)b * 2048 * 6144 + (size_t)h * 128;
    const u16* Kg = Qg + 2048;
    const u16* Vtg = vt + (size_t)bh * 128 * 2048;
    const float C2 = 0.12751743f;

    int srow[4], scol[4], pi0[4];
#pragma unroll
    for (int ci = 0; ci < 4; ++ci) {
        int idx = ci * 512 + t;
        int row = idx >> 4, c = idx & 15;
        srow[ci] = row;
        scol[ci] = c * 8;
        pi0[ci] = 32 * (c >> 2) + 16 * (c & 1) + 4 * ((c >> 1) & 1);
    }

    s16x8 qf[4];
#pragma unroll
    for (int kc = 0; kc < 4; ++kc)
        qf[kc] = *reinterpret_cast<const s16x8*>(
            Qg + (size_t)(q0 + wave * 16 + m16) * 6144 + kc * 32 + qd * 8);

    f32x4 accO[8] = {};
    float mrow = -1e30f, lrow = 0.f;

    for (int kt = 0; kt < 16; ++kt) {
        const int s0 = kt * 128;
        s16x8 kreg[4], vreg[4];
#pragma unroll
        for (int ci = 0; ci < 4; ++ci) {
            kreg[ci] = *reinterpret_cast<const s16x8*>(
                Kg + (size_t)(s0 + srow[ci]) * 6144 + scol[ci]);
            vreg[ci] = *reinterpret_cast<const s16x8*>(
                Vtg + (size_t)srow[ci] * 2048 + s0 + scol[ci]);
        }
        __syncthreads();
#pragma unroll
        for (int ci = 0; ci < 4; ++ci) {
            *reinterpret_cast<s16x8*>(&KS[srow[ci] * 136 + scol[ci]]) = kreg[ci];
            s16x4 lo = __builtin_shufflevector(vreg[ci], vreg[ci], 0, 1, 2, 3);
            s16x4 hi = __builtin_shufflevector(vreg[ci], vreg[ci], 4, 5, 6, 7);
            *reinterpret_cast<s16x4*>(&VS[srow[ci] * 136 + pi0[ci]]) = lo;
            *reinterpret_cast<s16x4*>(&VS[srow[ci] * 136 + pi0[ci] + 8]) = hi;
        }
        __syncthreads();

        f32x4 accS[8] = {};
#pragma unroll
        for (int kc = 0; kc < 4; ++kc)
#pragma unroll
            for (int nj = 0; nj < 8; ++nj) {
                s16x8 kf = *reinterpret_cast<const s16x8*>(
                    &KS[(nj * 16 + m16) * 136 + (kc * 4 + qd) * 8]);
                accS[nj] = __builtin_amdgcn_mfma_f32_16x16x32_bf16(kf, qf[kc], accS[nj], 0, 0, 0);
            }

        float mx = accS[0][0];
#pragma unroll
        for (int nj = 0; nj < 8; ++nj)
#pragma unroll
            for (int r = 0; r < 4; ++r) mx = fmaxf(mx, accS[nj][r]);
        mx *= C2;
        mx = fmaxf(mx, __shfl_xor(mx, 16));
        mx = fmaxf(mx, __shfl_xor(mx, 32));
        float mn = fmaxf(mrow, mx);
        float alpha = __builtin_amdgcn_exp2f(mrow - mn);
        mrow = mn;
        float ls = 0.f;
        s16x4 pk[8];
#pragma unroll
        for (int nj = 0; nj < 8; ++nj) {
            float p0 = __builtin_amdgcn_exp2f(fmaf(accS[nj][0], C2, -mn));
            float p1 = __builtin_amdgcn_exp2f(fmaf(accS[nj][1], C2, -mn));
            float p2 = __builtin_amdgcn_exp2f(fmaf(accS[nj][2], C2, -mn));
            float p3 = __builtin_amdgcn_exp2f(fmaf(accS[nj][3], C2, -mn));
            ls += (p0 + p1) + (p2 + p3);
            u32 lo = pack_bf16_rhu(p0, p1);
            u32 hi = pack_bf16_rhu(p2, p3);
            uint2 pr = make_uint2(lo, hi);
            pk[nj] = __builtin_bit_cast(s16x4, pr);
        }
        ls += __shfl_xor(ls, 16);
        ls += __shfl_xor(ls, 32);
        lrow = lrow * alpha + ls;
        float aO[4];
#pragma unroll
        for (int r = 0; r < 4; ++r) aO[r] = __shfl(alpha, qd * 4 + r);
#pragma unroll
        for (int dj = 0; dj < 8; ++dj)
#pragma unroll
            for (int r = 0; r < 4; ++r) accO[dj][r] *= aO[r];

#pragma unroll
        for (int kb = 0; kb < 4; ++kb) {
            s16x8 af = __builtin_shufflevector(pk[2 * kb], pk[2 * kb + 1],
                                               0, 1, 2, 3, 4, 5, 6, 7);
#pragma unroll
            for (int dj = 0; dj < 8; ++dj) {
                s16x8 vf = *reinterpret_cast<const s16x8*>(
                    &VS[(dj * 16 + m16) * 136 + kb * 32 + qd * 8]);
                accO[dj] = __builtin_amdgcn_mfma_f32_16x16x32_bf16(af, vf, accO[dj], 0, 0, 0);
            }
        }
    }
    float invl = 1.0f / lrow;
    float iv[4];
#pragma unroll
    for (int r = 0; r < 4; ++r) iv[r] = __shfl(invl, qd * 4 + r);
#pragma unroll
    for (int r = 0; r < 4; ++r) {
        size_t row = (size_t)b * 2048 + q0 + wave * 16 + qd * 4 + r;
#pragma unroll
        for (int dj = 0; dj < 8; ++dj)
            out[row * 2048 + h * 128 + dj * 16 + m16] =
                f32_to_bf16_rne(accO[dj][r] * iv[r]);
    }
}

// ---------- launch ----------
extern "C" void kernel_launch(void* const* d_in, const int* in_sizes, int n_in,
                              void* d_out, int out_size, void* d_ws, size_t ws_size,
                              hipStream_t stream) {
    const float* x     = (const float*)d_in[0];
    const float* W_qkv = (const float*)d_in[1];
    const float* W_out = (const float*)d_in[2];
    float* out = (float*)d_out;

    char* ws = (char*)d_ws;
    u16* xb   = (u16*)(ws);
    u16* Wqt  = (u16*)(ws + (16u << 20));
    u16* Wot  = (u16*)(ws + (40u << 20));
    u16* qkvb = (u16*)(ws + (48u << 20));
    u16* attn = (u16*)(ws + (96u << 20));
    u16* vtg  = (u16*)(ws + (112u << 20));

    k_cast<<<4096, 256, 0, stream>>>(x, xb);
    k_transpose_cast<<<dim3(96, 16), 256, 0, stream>>>(W_qkv, Wqt, 2048, 6144);
    k_transpose_cast<<<dim3(32, 16), 256, 0, stream>>>(W_out, Wot, 2048, 2048);
    k_gemm256<true, true><<<dim3(24, 16), 512, 0, stream>>>(xb, Wqt, qkvb, 4096, 6144, 2048);
    k_transpose_v<<<dim3(16, 32), 256, 0, stream>>>(qkvb, vtg);
    k_flash<<<dim3(16, 32), 512, 0, stream>>>(qkvb, vtg, attn);
    k_gemm_bt<false, false><<<dim3(16, 32), 256, 0, stream>>>(attn, Wot, out, 4096, 2048, 2048);
}

// Round 4
// 401.754 us; speedup vs baseline: 1.0334x; 1.0175x over previous
//
#include <hip/hip_runtime.h>
#include <math.h>

typedef float  f32x4 __attribute__((ext_vector_type(4)));
typedef short  s16x8 __attribute__((ext_vector_type(8)));
typedef short  s16x4 __attribute__((ext_vector_type(4)));
typedef unsigned short u16;
typedef unsigned int u32;

// ---------- bf16 helpers ----------
static __device__ __forceinline__ u16 f32_to_bf16_rne(float f) {
    u32 u = __builtin_bit_cast(u32, f);
    u32 r = u + 0x7fffu + ((u >> 16) & 1u);
    return (u16)(r >> 16);
}
static __device__ __forceinline__ u32 pack_bf16_rhu(float a, float b) {
    u32 ua = __builtin_bit_cast(u32, a);
    u32 ub = __builtin_bit_cast(u32, b);
    return ((ua + 0x8000u) >> 16) | ((ub + 0x8000u) & 0xffff0000u);
}
static __device__ __forceinline__ float bf16_to_f32(u16 h) {
    return __builtin_bit_cast(float, (u32)h << 16);
}

// async global->LDS 16B (lane-contiguous LDS dest ONLY; source is per-lane)
static __device__ __forceinline__ void gl2lds16(const void* g, void* l) {
    __builtin_amdgcn_global_load_lds(
        (const __attribute__((address_space(1))) u32*)g,
        (__attribute__((address_space(3))) u32*)l, 16, 0, 0);
}

// ---------- 1) cast fp32 -> bf16 ----------
__global__ __launch_bounds__(256) void k_cast(const float* __restrict__ in,
                                              u16* __restrict__ out) {
    int i = (blockIdx.x * 256 + threadIdx.x) * 8;
    float4 a = *reinterpret_cast<const float4*>(in + i);
    float4 b = *reinterpret_cast<const float4*>(in + i + 4);
    s16x8 o;
    o[0] = (short)f32_to_bf16_rne(a.x); o[1] = (short)f32_to_bf16_rne(a.y);
    o[2] = (short)f32_to_bf16_rne(a.z); o[3] = (short)f32_to_bf16_rne(a.w);
    o[4] = (short)f32_to_bf16_rne(b.x); o[5] = (short)f32_to_bf16_rne(b.y);
    o[6] = (short)f32_to_bf16_rne(b.z); o[7] = (short)f32_to_bf16_rne(b.w);
    *reinterpret_cast<s16x8*>(out + i) = o;
}

// ---------- 2) transpose + cast ----------
__global__ __launch_bounds__(256) void k_transpose_cast(const float* __restrict__ in,
                                                        u16* __restrict__ out,
                                                        int R, int C) {
    __shared__ float TT[64 * 130];
    const int t = threadIdx.x;
    const int ct = blockIdx.x, rt = blockIdx.y;
    const int tr = t >> 4;
    const int tc = t & 15;
    float4 v[8];
#pragma unroll
    for (int u = 0; u < 8; ++u) {
        int r = u * 16 + tr;
        v[u] = *reinterpret_cast<const float4*>(in + (size_t)(rt * 128 + r) * C + ct * 64 + tc * 4);
    }
#pragma unroll
    for (int u = 0; u < 8; ++u) {
        int r = u * 16 + tr;
        TT[(tc * 4 + 0) * 130 + r] = v[u].x;
        TT[(tc * 4 + 1) * 130 + r] = v[u].y;
        TT[(tc * 4 + 2) * 130 + r] = v[u].z;
        TT[(tc * 4 + 3) * 130 + r] = v[u].w;
    }
    __syncthreads();
#pragma unroll
    for (int u = 0; u < 4; ++u) {
        int oc = u * 16 + tr;
        int r0 = tc * 8;
        s16x8 o;
#pragma unroll
        for (int e = 0; e < 8; ++e)
            o[e] = (short)f32_to_bf16_rne(TT[oc * 130 + r0 + e]);
        *reinterpret_cast<s16x8*>(out + (size_t)(ct * 64 + oc) * R + rt * 128 + r0) = o;
    }
}

// ---------- 3a) m97-style 128x128 GEMM (kept for out-projection) ----------
template<bool BF16OUT, bool ROPE>
__global__ __launch_bounds__(256) void k_gemm_bt(const u16* __restrict__ Amat,
                                                 const u16* __restrict__ Bt,
                                                 void* __restrict__ Cout,
                                                 int M, int N, int K) {
    __shared__ __align__(16) u16 As[128 * 64];
    __shared__ __align__(16) u16 Bs[128 * 64];
    const int t = threadIdx.x;
    const int lane = t & 63, wave = t >> 6;
    const int m16 = lane & 15, qd = lane >> 4;
    const int wm = (wave >> 1) * 64, wn = (wave & 1) * 64;
    const size_t m0 = (size_t)blockIdx.y * 128, n0 = (size_t)blockIdx.x * 128;
    const int srow = lane >> 3;
    const int schunk = (lane & 7) ^ srow;

    f32x4 acc[4][4] = {};

    for (int k0 = 0; k0 < K; k0 += 64) {
#pragma unroll
        for (int j = 0; j < 4; ++j) {
            int rbase = j * 32 + wave * 8;
            int r = rbase + srow;
            gl2lds16(Amat + (m0 + r) * (size_t)K + k0 + schunk * 8, &As[rbase * 64]);
            gl2lds16(Bt   + (n0 + r) * (size_t)K + k0 + schunk * 8, &Bs[rbase * 64]);
        }
        __syncthreads();
#pragma unroll
        for (int kh = 0; kh < 2; ++kh) {
            s16x8 af[4], bf[4];
#pragma unroll
            for (int i = 0; i < 4; ++i) {
                int ra = wm + i * 16 + m16;
                int pa = (kh * 4 + qd) ^ (ra & 7);
                af[i] = *reinterpret_cast<const s16x8*>(&As[ra * 64 + pa * 8]);
                int rb = wn + i * 16 + m16;
                int pb = (kh * 4 + qd) ^ (rb & 7);
                bf[i] = *reinterpret_cast<const s16x8*>(&Bs[rb * 64 + pb * 8]);
            }
#pragma unroll
            for (int i = 0; i < 4; ++i)
#pragma unroll
                for (int jj = 0; jj < 4; ++jj)
                    acc[i][jj] = __builtin_amdgcn_mfma_f32_16x16x32_bf16(af[i], bf[jj], acc[i][jj], 0, 0, 0);
        }
        __syncthreads();
    }
    if (ROPE && n0 < 4096) {
        float invf[4];
#pragma unroll
        for (int j = 0; j < 4; ++j) {
            int pi = ((int)(wn + j * 16 + m16) & 127) >> 1;
            invf[j] = __expf(-0.14391156831f * (float)pi);
        }
#pragma unroll
        for (int i = 0; i < 4; ++i)
#pragma unroll
            for (int j = 0; j < 4; ++j)
#pragma unroll
                for (int r = 0; r < 4; ++r) {
                    float v = acc[i][j][r];
                    float p = __shfl_xor(v, 1);
                    size_t row = m0 + wm + i * 16 + qd * 4 + r;
                    float f = (float)(int)(row & 2047) * invf[j];
                    float sn, cs;
                    __sincosf(f, &sn, &cs);
                    float res = (m16 & 1) ? fmaf(p, sn, v * cs) : fmaf(v, cs, -p * sn);
                    size_t col = n0 + wn + j * 16 + m16;
                    ((u16*)Cout)[row * N + col] = f32_to_bf16_rne(res);
                }
    } else {
#pragma unroll
        for (int i = 0; i < 4; ++i)
#pragma unroll
            for (int j = 0; j < 4; ++j)
#pragma unroll
                for (int r = 0; r < 4; ++r) {
                    size_t row = m0 + wm + i * 16 + qd * 4 + r;
                    size_t col = n0 + wn + j * 16 + m16;
                    if (BF16OUT)
                        ((u16*)Cout)[row * N + col] = f32_to_bf16_rne(acc[i][j][r]);
                    else
                        ((float*)Cout)[row * N + col] = acc[i][j][r];
                }
    }
}

// ---------- 3b) NEW: 128x384-tile GEMM, tail-free + read/MFMA overlap (v4) ----------
// Grid 16x32 = 512 blocks = EXACTLY 2 occupancy rounds (no tail).
// 8 waves (2M x 4N), per-wave 64x96: acc[4][6] = 96 AGPR -> 2 waves/SIMD.
// LDS: As[2][128*64] + Bs[2][384*64] = 128 KiB.
// Per K-tile, only 2 barriers:
//   region1: issue ALL 20 ds_reads (kh0+kh1) + stage B2(t+1),A(t+1)->p^1;
//            24 MFMA (kh0) — compiler's counted lgkm releases kh0 cluster
//            while kh1 reads complete UNDER the MFMAs (pipes overlap).
//            lgkmcnt(0) (free: reads ~900cy old) ; B_mid  [WAR: p reads done]
//   region2: stage B0(t+2),B1(t+2)->p ; 24 MFMA (kh1) ; vmcnt(4) ; B_end
// vmcnt(4) retires exactly tile t+1's 8 loads; B0/B1(t+2) stay in flight.
template<bool BF16OUT, bool ROPE>
__global__ __launch_bounds__(512, 2) void k_gemm384(const u16* __restrict__ Amat,
                                                    const u16* __restrict__ Bt,
                                                    void* __restrict__ Cout,
                                                    int M, int N, int K) {
    __shared__ __align__(16) u16 As[2][128 * 64];
    __shared__ __align__(16) u16 Bs[2][384 * 64];
    const int t = threadIdx.x;
    const int lane = t & 63, wave = t >> 6;
    const int m16 = lane & 15, qd = lane >> 4;
    const int wr = wave >> 2, wc = wave & 3;          // 2M x 4N wave grid
    const int srow = lane >> 3;                        // 0..7
    const int sch = (lane & 7) ^ srow;                 // pre-swizzled global k-chunk

    // chunked XCD-aware swizzle for grid 16x32 (8 XCDs, each 4bx x 16by)
    int bx, by;
    if (gridDim.x == 16 && gridDim.y == 32) {
        int orig = blockIdx.y * gridDim.x + blockIdx.x;
        int xcd = orig & 7, loc = orig >> 3;           // loc 0..63
        int cx = xcd & 3, cy = xcd >> 2;
        bx = cx * 4 + (loc & 3);
        by = cy * 16 + (loc >> 2);
    } else {
        bx = blockIdx.x; by = blockIdx.y;
    }
    const size_t m0 = (size_t)by * 128, n0 = (size_t)bx * 384;

    const u16* Ab = Amat + m0 * (size_t)K;
    const u16* Bb = Bt + n0 * (size_t)K;
    const int NT = K >> 6;

    // stage 128 rows (2 x gl2lds/thread; LDS linear, global pre-swizzled)
    auto stage128 = [&](const u16* gbase, u16* lbase, int k0) {
        int rb0 = wave * 8;
        gl2lds16(gbase + (size_t)(rb0 + srow) * K + k0 + sch * 8, lbase + rb0 * 64);
        int rb1 = rb0 + 64;
        gl2lds16(gbase + (size_t)(rb1 + srow) * K + k0 + sch * 8, lbase + rb1 * 64);
    };

    f32x4 acc[4][6] = {};
    s16x8 af[4][2], bq[6][2];

    // ---- prologue: tile0 (B0,B1,B2,A) -> buf0 ; B0,B1(1) -> buf1 ; vmcnt(4) ----
    stage128(Bb,            &Bs[0][0],        0);
    stage128(Bb + 128 * (size_t)K, &Bs[0][128 * 64], 0);
    stage128(Bb + 256 * (size_t)K, &Bs[0][256 * 64], 0);
    stage128(Ab,            &As[0][0],        0);
    if (NT > 1) {
        stage128(Bb,            &Bs[1][0],        64);
        stage128(Bb + 128 * (size_t)K, &Bs[1][128 * 64], 64);
        asm volatile("s_waitcnt vmcnt(4)" ::: "memory");   // tile0's 8 loads landed
    } else {
        asm volatile("s_waitcnt vmcnt(0)" ::: "memory");
    }
    __builtin_amdgcn_s_barrier();

    for (int kt = 0; kt < NT; ++kt) {
        const int p = kt & 1;

        // ===== region 1: all reads (kh0+kh1); stage B2(t+1),A(t+1)->p^1; MFMA kh0 =====
#pragma unroll
        for (int i = 0; i < 4; ++i) {
            int ra = wr * 64 + i * 16 + m16;
            af[i][0] = *reinterpret_cast<const s16x8*>(&As[p][ra * 64 + ((qd)     ^ (ra & 7)) * 8]);
        }
#pragma unroll
        for (int j = 0; j < 6; ++j) {
            int rb = wc * 96 + j * 16 + m16;
            bq[j][0] = *reinterpret_cast<const s16x8*>(&Bs[p][rb * 64 + ((qd)     ^ (rb & 7)) * 8]);
        }
        if (kt + 1 < NT) stage128(Bb + 256 * (size_t)K, &Bs[p ^ 1][256 * 64], (kt + 1) << 6);
#pragma unroll
        for (int i = 0; i < 4; ++i) {
            int ra = wr * 64 + i * 16 + m16;
            af[i][1] = *reinterpret_cast<const s16x8*>(&As[p][ra * 64 + ((4 + qd) ^ (ra & 7)) * 8]);
        }
#pragma unroll
        for (int j = 0; j < 6; ++j) {
            int rb = wc * 96 + j * 16 + m16;
            bq[j][1] = *reinterpret_cast<const s16x8*>(&Bs[p][rb * 64 + ((4 + qd) ^ (rb & 7)) * 8]);
        }
        if (kt + 1 < NT) stage128(Ab, &As[p ^ 1][0], (kt + 1) << 6);

        __builtin_amdgcn_s_setprio(1);
#pragma unroll
        for (int i = 0; i < 4; ++i)
#pragma unroll
            for (int j = 0; j < 6; ++j)
                acc[i][j] = __builtin_amdgcn_mfma_f32_16x16x32_bf16(af[i][0], bq[j][0], acc[i][j], 0, 0, 0);
        __builtin_amdgcn_s_setprio(0);

        asm volatile("s_waitcnt lgkmcnt(0)" ::: "memory");   // ~free; WAR guard for B_mid
        __builtin_amdgcn_s_barrier();                        // B_mid: p reads done

        // ===== region 2: stage B0,B1(t+2)->p; MFMA kh1; counted vmcnt; B_end =====
        if (kt + 2 < NT) {
            stage128(Bb,            &Bs[p][0],        (kt + 2) << 6);
            stage128(Bb + 128 * (size_t)K, &Bs[p][128 * 64], (kt + 2) << 6);
        }
        __builtin_amdgcn_s_setprio(1);
#pragma unroll
        for (int i = 0; i < 4; ++i)
#pragma unroll
            for (int j = 0; j < 6; ++j)
                acc[i][j] = __builtin_amdgcn_mfma_f32_16x16x32_bf16(af[i][1], bq[j][1], acc[i][j], 0, 0, 0);
        __builtin_amdgcn_s_setprio(0);
        if (kt + 2 < NT) {
            asm volatile("s_waitcnt vmcnt(4)" ::: "memory"); // retires tile t+1 exactly
        } else {
            asm volatile("s_waitcnt vmcnt(0)" ::: "memory");
        }
        __builtin_amdgcn_s_barrier();                        // B_end
    }

    // ---- epilogue (per-16-col ROPE guard: 384 does not divide 4096) ----
    if (ROPE) {
        float invf[6];
#pragma unroll
        for (int j = 0; j < 6; ++j) {
            int pi = ((int)(n0 + wc * 96 + j * 16 + m16) & 127) >> 1;
            invf[j] = __expf(-0.14391156831f * (float)pi);
        }
#pragma unroll
        for (int i = 0; i < 4; ++i)
#pragma unroll
            for (int j = 0; j < 6; ++j) {
                size_t colbase = n0 + wc * 96 + j * 16;
                if (colbase < 4096) {
#pragma unroll
                    for (int r = 0; r < 4; ++r) {
                        float v = acc[i][j][r];
                        float pv = __shfl_xor(v, 1);
                        size_t row = m0 + wr * 64 + i * 16 + qd * 4 + r;
                        float f = (float)(int)(row & 2047) * invf[j];
                        float sn, cs;
                        __sincosf(f, &sn, &cs);
                        float res = (m16 & 1) ? fmaf(pv, sn, v * cs) : fmaf(v, cs, -pv * sn);
                        ((u16*)Cout)[row * N + colbase + m16] = f32_to_bf16_rne(res);
                    }
                } else {
#pragma unroll
                    for (int r = 0; r < 4; ++r) {
                        size_t row = m0 + wr * 64 + i * 16 + qd * 4 + r;
                        ((u16*)Cout)[row * N + colbase + m16] = f32_to_bf16_rne(acc[i][j][r]);
                    }
                }
            }
    } else {
#pragma unroll
        for (int i = 0; i < 4; ++i)
#pragma unroll
            for (int j = 0; j < 6; ++j)
#pragma unroll
                for (int r = 0; r < 4; ++r) {
                    size_t row = m0 + wr * 64 + i * 16 + qd * 4 + r;
                    size_t col = n0 + wc * 96 + j * 16 + m16;
                    if (BF16OUT)
                        ((u16*)Cout)[row * N + col] = f32_to_bf16_rne(acc[i][j][r]);
                    else
                        ((float*)Cout)[row * N + col] = acc[i][j][r];
                }
    }
}

// ---------- 4) V -> V^T ----------
__global__ __launch_bounds__(256) void k_transpose_v(const u16* __restrict__ qkv,
                                                     u16* __restrict__ vt) {
    __shared__ u16 TT[128 * 130];
    const int t = threadIdx.x;
    const int st = blockIdx.x;
    const int bh = blockIdx.y;
    const int b = bh >> 4, h = bh & 15;
    const u16* src = qkv + (size_t)b * 2048 * 6144 + 4096 + (size_t)h * 128;
    const int tr = t >> 4, tc = t & 15;
    s16x8 v[8];
#pragma unroll
    for (int u = 0; u < 8; ++u) {
        int s = u * 16 + tr;
        v[u] = *reinterpret_cast<const s16x8*>(src + (size_t)(st * 128 + s) * 6144 + tc * 8);
    }
#pragma unroll
    for (int u = 0; u < 8; ++u) {
        int s = u * 16 + tr;
#pragma unroll
        for (int e = 0; e < 8; ++e)
            TT[(tc * 8 + e) * 130 + s] = (u16)v[u][e];
    }
    __syncthreads();
    u16* dst = vt + (size_t)bh * 128 * 2048 + st * 128;
#pragma unroll
    for (int u = 0; u < 8; ++u) {
        int d = u * 16 + tr;
        int s0 = tc * 8;
        s16x8 o;
#pragma unroll
        for (int e = 0; e < 8; ++e) o[e] = (short)TT[d * 130 + s0 + e];
        *reinterpret_cast<s16x8*>(dst + (size_t)d * 2048 + s0) = o;
    }
}

// ---------- 5) flash attention (unchanged — protected win) ----------
__global__ __launch_bounds__(512, 4) void k_flash(const u16* __restrict__ qkv,
                                                  const u16* __restrict__ vt,
                                                  u16* __restrict__ out) {
    __shared__ __align__(16) u16 KS[128 * 136];
    __shared__ __align__(16) u16 VS[128 * 136];
    const int t = threadIdx.x, lane = t & 63, wave = t >> 6;
    const int m16 = lane & 15, qd = lane >> 4;
    const int bh = blockIdx.y, b = bh >> 4, h = bh & 15;
    const int q0 = blockIdx.x * 128;
    const u16* Qg = qkv + (size_t)b * 2048 * 6144 + (size_t)h * 128;
    const u16* Kg = Qg + 2048;
    const u16* Vtg = vt + (size_t)bh * 128 * 2048;
    const float C2 = 0.12751743f;

    int srow[4], scol[4], pi0[4];
#pragma unroll
    for (int ci = 0; ci < 4; ++ci) {
        int idx = ci * 512 + t;
        int row = idx >> 4, c = idx & 15;
        srow[ci] = row;
        scol[ci] = c * 8;
        pi0[ci] = 32 * (c >> 2) + 16 * (c & 1) + 4 * ((c >> 1) & 1);
    }

    s16x8 qf[4];
#pragma unroll
    for (int kc = 0; kc < 4; ++kc)
        qf[kc] = *reinterpret_cast<const s16x8*>(
            Qg + (size_t)(q0 + wave * 16 + m16) * 6144 + kc * 32 + qd * 8);

    f32x4 accO[8] = {};
    float mrow = -1e30f, lrow = 0.f;

    for (int kt = 0; kt < 16; ++kt) {
        const int s0 = kt * 128;
        s16x8 kreg[4], vreg[4];
#pragma unroll
        for (int ci = 0; ci < 4; ++ci) {
            kreg[ci] = *reinterpret_cast<const s16x8*>(
                Kg + (size_t)(s0 + srow[ci]) * 6144 + scol[ci]);
            vreg[ci] = *reinterpret_cast<const s16x8*>(
                Vtg + (size_t)srow[ci] * 2048 + s0 + scol[ci]);
        }
        __syncthreads();
#pragma unroll
        for (int ci = 0; ci < 4; ++ci) {
            *reinterpret_cast<s16x8*>(&KS[srow[ci] * 136 + scol[ci]]) = kreg[ci];
            s16x4 lo = __builtin_shufflevector(vreg[ci], vreg[ci], 0, 1, 2, 3);
            s16x4 hi = __builtin_shufflevector(vreg[ci], vreg[ci], 4, 5, 6, 7);
            *reinterpret_cast<s16x4*>(&VS[srow[ci] * 136 + pi0[ci]]) = lo;
            *reinterpret_cast<s16x4*>(&VS[srow[ci] * 136 + pi0[ci] + 8]) = hi;
        }
        __syncthreads();

        f32x4 accS[8] = {};
#pragma unroll
        for (int kc = 0; kc < 4; ++kc)
#pragma unroll
            for (int nj = 0; nj < 8; ++nj) {
                s16x8 kf = *reinterpret_cast<const s16x8*>(
                    &KS[(nj * 16 + m16) * 136 + (kc * 4 + qd) * 8]);
                accS[nj] = __builtin_amdgcn_mfma_f32_16x16x32_bf16(kf, qf[kc], accS[nj], 0, 0, 0);
            }

        float mx = accS[0][0];
#pragma unroll
        for (int nj = 0; nj < 8; ++nj)
#pragma unroll
            for (int r = 0; r < 4; ++r) mx = fmaxf(mx, accS[nj][r]);
        mx *= C2;
        mx = fmaxf(mx, __shfl_xor(mx, 16));
        mx = fmaxf(mx, __shfl_xor(mx, 32));
        float mn = fmaxf(mrow, mx);
        float alpha = __builtin_amdgcn_exp2f(mrow - mn);
        mrow = mn;
        float ls = 0.f;
        s16x4 pk[8];
#pragma unroll
        for (int nj = 0; nj < 8; ++nj) {
            float p0 = __builtin_amdgcn_exp2f(fmaf(accS[nj][0], C2, -mn));
            float p1 = __builtin_amdgcn_exp2f(fmaf(accS[nj][1], C2, -mn));
            float p2 = __builtin_amdgcn_exp2f(fmaf(accS[nj][2], C2, -mn));
            float p3 = __builtin_amdgcn_exp2f(fmaf(accS[nj][3], C2, -mn));
            ls += (p0 + p1) + (p2 + p3);
            u32 lo = pack_bf16_rhu(p0, p1);
            u32 hi = pack_bf16_rhu(p2, p3);
            uint2 pr = make_uint2(lo, hi);
            pk[nj] = __builtin_bit_cast(s16x4, pr);
        }
        ls += __shfl_xor(ls, 16);
        ls += __shfl_xor(ls, 32);
        lrow = lrow * alpha + ls;
        float aO[4];
#pragma unroll
        for (int r = 0; r < 4; ++r) aO[r] = __shfl(alpha, qd * 4 + r);
#pragma unroll
        for (int dj = 0; dj < 8; ++dj)
#pragma unroll
            for (int r = 0; r < 4; ++r) accO[dj][r] *= aO[r];

#pragma unroll
        for (int kb = 0; kb < 4; ++kb) {
            s16x8 af = __builtin_shufflevector(pk[2 * kb], pk[2 * kb + 1],
                                               0, 1, 2, 3, 4, 5, 6, 7);
#pragma unroll
            for (int dj = 0; dj < 8; ++dj) {
                s16x8 vf = *reinterpret_cast<const s16x8*>(
                    &VS[(dj * 16 + m16) * 136 + kb * 32 + qd * 8]);
                accO[dj] = __builtin_amdgcn_mfma_f32_16x16x32_bf16(af, vf, accO[dj], 0, 0, 0);
            }
        }
    }
    float invl = 1.0f / lrow;
    float iv[4];
#pragma unroll
    for (int r = 0; r < 4; ++r) iv[r] = __shfl(invl, qd * 4 + r);
#pragma unroll
    for (int r = 0; r < 4; ++r) {
        size_t row = (size_t)b * 2048 + q0 + wave * 16 + qd * 4 + r;
#pragma unroll
        for (int dj = 0; dj < 8; ++dj)
            out[row * 2048 + h * 128 + dj * 16 + m16] =
                f32_to_bf16_rne(accO[dj][r] * iv[r]);
    }
}

// ---------- launch ----------
extern "C" void kernel_launch(void* const* d_in, const int* in_sizes, int n_in,
                              void* d_out, int out_size, void* d_ws, size_t ws_size,
                              hipStream_t stream) {
    const float* x     = (const float*)d_in[0];
    const float* W_qkv = (const float*)d_in[1];
    const float* W_out = (const float*)d_in[2];
    float* out = (float*)d_out;

    char* ws = (char*)d_ws;
    u16* xb   = (u16*)(ws);
    u16* Wqt  = (u16*)(ws + (16u << 20));
    u16* Wot  = (u16*)(ws + (40u << 20));
    u16* qkvb = (u16*)(ws + (48u << 20));
    u16* attn = (u16*)(ws + (96u << 20));
    u16* vtg  = (u16*)(ws + (112u << 20));

    k_cast<<<4096, 256, 0, stream>>>(x, xb);
    k_transpose_cast<<<dim3(96, 16), 256, 0, stream>>>(W_qkv, Wqt, 2048, 6144);
    k_transpose_cast<<<dim3(32, 16), 256, 0, stream>>>(W_out, Wot, 2048, 2048);
    k_gemm384<true, true><<<dim3(16, 32), 512, 0, stream>>>(xb, Wqt, qkvb, 4096, 6144, 2048);
    k_transpose_v<<<dim3(16, 32), 256, 0, stream>>>(qkvb, vtg);
    k_flash<<<dim3(16, 32), 512, 0, stream>>>(qkvb, vtg, attn);
    k_gemm_bt<false, false><<<dim3(16, 32), 256, 0, stream>>>(attn, Wot, out, 4096, 2048, 2048);
}

// Round 5
// 400.708 us; speedup vs baseline: 1.0361x; 1.0026x over previous
//
#include <hip/hip_runtime.h>
#include <math.h>

typedef float  f32x4  __attribute__((ext_vector_type(4)));
typedef float  f32x16 __attribute__((ext_vector_type(16)));
typedef short  s16x8 __attribute__((ext_vector_type(8)));
typedef short  s16x4 __attribute__((ext_vector_type(4)));
typedef unsigned short u16;
typedef unsigned int u32;

// ---------- bf16 helpers ----------
static __device__ __forceinline__ u16 f32_to_bf16_rne(float f) {
    u32 u = __builtin_bit_cast(u32, f);
    u32 r = u + 0x7fffu + ((u >> 16) & 1u);
    return (u16)(r >> 16);
}
static __device__ __forceinline__ u32 pack_bf16_rhu(float a, float b) {
    u32 ua = __builtin_bit_cast(u32, a);
    u32 ub = __builtin_bit_cast(u32, b);
    return ((ua + 0x8000u) >> 16) | ((ub + 0x8000u) & 0xffff0000u);
}
static __device__ __forceinline__ float bf16_to_f32(u16 h) {
    return __builtin_bit_cast(float, (u32)h << 16);
}

// async global->LDS 16B (lane-contiguous LDS dest ONLY; source is per-lane)
static __device__ __forceinline__ void gl2lds16(const void* g, void* l) {
    __builtin_amdgcn_global_load_lds(
        (const __attribute__((address_space(1))) u32*)g,
        (__attribute__((address_space(3))) u32*)l, 16, 0, 0);
}

// ---------- 1) cast fp32 -> bf16 ----------
__global__ __launch_bounds__(256) void k_cast(const float* __restrict__ in,
                                              u16* __restrict__ out) {
    int i = (blockIdx.x * 256 + threadIdx.x) * 8;
    float4 a = *reinterpret_cast<const float4*>(in + i);
    float4 b = *reinterpret_cast<const float4*>(in + i + 4);
    s16x8 o;
    o[0] = (short)f32_to_bf16_rne(a.x); o[1] = (short)f32_to_bf16_rne(a.y);
    o[2] = (short)f32_to_bf16_rne(a.z); o[3] = (short)f32_to_bf16_rne(a.w);
    o[4] = (short)f32_to_bf16_rne(b.x); o[5] = (short)f32_to_bf16_rne(b.y);
    o[6] = (short)f32_to_bf16_rne(b.z); o[7] = (short)f32_to_bf16_rne(b.w);
    *reinterpret_cast<s16x8*>(out + i) = o;
}

// ---------- 2) transpose + cast ----------
__global__ __launch_bounds__(256) void k_transpose_cast(const float* __restrict__ in,
                                                        u16* __restrict__ out,
                                                        int R, int C) {
    __shared__ float TT[64 * 130];
    const int t = threadIdx.x;
    const int ct = blockIdx.x, rt = blockIdx.y;
    const int tr = t >> 4;
    const int tc = t & 15;
    float4 v[8];
#pragma unroll
    for (int u = 0; u < 8; ++u) {
        int r = u * 16 + tr;
        v[u] = *reinterpret_cast<const float4*>(in + (size_t)(rt * 128 + r) * C + ct * 64 + tc * 4);
    }
#pragma unroll
    for (int u = 0; u < 8; ++u) {
        int r = u * 16 + tr;
        TT[(tc * 4 + 0) * 130 + r] = v[u].x;
        TT[(tc * 4 + 1) * 130 + r] = v[u].y;
        TT[(tc * 4 + 2) * 130 + r] = v[u].z;
        TT[(tc * 4 + 3) * 130 + r] = v[u].w;
    }
    __syncthreads();
#pragma unroll
    for (int u = 0; u < 4; ++u) {
        int oc = u * 16 + tr;
        int r0 = tc * 8;
        s16x8 o;
#pragma unroll
        for (int e = 0; e < 8; ++e)
            o[e] = (short)f32_to_bf16_rne(TT[oc * 130 + r0 + e]);
        *reinterpret_cast<s16x8*>(out + (size_t)(ct * 64 + oc) * R + rt * 128 + r0) = o;
    }
}

// ---------- 3a) m97-style 128x128 GEMM (kept for out-projection) ----------
template<bool BF16OUT, bool ROPE>
__global__ __launch_bounds__(256) void k_gemm_bt(const u16* __restrict__ Amat,
                                                 const u16* __restrict__ Bt,
                                                 void* __restrict__ Cout,
                                                 int M, int N, int K) {
    __shared__ __align__(16) u16 As[128 * 64];
    __shared__ __align__(16) u16 Bs[128 * 64];
    const int t = threadIdx.x;
    const int lane = t & 63, wave = t >> 6;
    const int m16 = lane & 15, qd = lane >> 4;
    const int wm = (wave >> 1) * 64, wn = (wave & 1) * 64;
    const size_t m0 = (size_t)blockIdx.y * 128, n0 = (size_t)blockIdx.x * 128;
    const int srow = lane >> 3;
    const int schunk = (lane & 7) ^ srow;

    f32x4 acc[4][4] = {};

    for (int k0 = 0; k0 < K; k0 += 64) {
#pragma unroll
        for (int j = 0; j < 4; ++j) {
            int rbase = j * 32 + wave * 8;
            int r = rbase + srow;
            gl2lds16(Amat + (m0 + r) * (size_t)K + k0 + schunk * 8, &As[rbase * 64]);
            gl2lds16(Bt   + (n0 + r) * (size_t)K + k0 + schunk * 8, &Bs[rbase * 64]);
        }
        __syncthreads();
#pragma unroll
        for (int kh = 0; kh < 2; ++kh) {
            s16x8 af[4], bf[4];
#pragma unroll
            for (int i = 0; i < 4; ++i) {
                int ra = wm + i * 16 + m16;
                int pa = (kh * 4 + qd) ^ (ra & 7);
                af[i] = *reinterpret_cast<const s16x8*>(&As[ra * 64 + pa * 8]);
                int rb = wn + i * 16 + m16;
                int pb = (kh * 4 + qd) ^ (rb & 7);
                bf[i] = *reinterpret_cast<const s16x8*>(&Bs[rb * 64 + pb * 8]);
            }
#pragma unroll
            for (int i = 0; i < 4; ++i)
#pragma unroll
                for (int jj = 0; jj < 4; ++jj)
                    acc[i][jj] = __builtin_amdgcn_mfma_f32_16x16x32_bf16(af[i], bf[jj], acc[i][jj], 0, 0, 0);
        }
        __syncthreads();
    }
    if (ROPE && n0 < 4096) {
        float invf[4];
#pragma unroll
        for (int j = 0; j < 4; ++j) {
            int pi = ((int)(wn + j * 16 + m16) & 127) >> 1;
            invf[j] = __expf(-0.14391156831f * (float)pi);
        }
#pragma unroll
        for (int i = 0; i < 4; ++i)
#pragma unroll
            for (int j = 0; j < 4; ++j)
#pragma unroll
                for (int r = 0; r < 4; ++r) {
                    float v = acc[i][j][r];
                    float p = __shfl_xor(v, 1);
                    size_t row = m0 + wm + i * 16 + qd * 4 + r;
                    float f = (float)(int)(row & 2047) * invf[j];
                    float sn, cs;
                    __sincosf(f, &sn, &cs);
                    float res = (m16 & 1) ? fmaf(p, sn, v * cs) : fmaf(v, cs, -p * sn);
                    size_t col = n0 + wn + j * 16 + m16;
                    ((u16*)Cout)[row * N + col] = f32_to_bf16_rne(res);
                }
    } else {
#pragma unroll
        for (int i = 0; i < 4; ++i)
#pragma unroll
            for (int j = 0; j < 4; ++j)
#pragma unroll
                for (int r = 0; r < 4; ++r) {
                    size_t row = m0 + wm + i * 16 + qd * 4 + r;
                    size_t col = n0 + wn + j * 16 + m16;
                    if (BF16OUT)
                        ((u16*)Cout)[row * N + col] = f32_to_bf16_rne(acc[i][j][r]);
                    else
                        ((float*)Cout)[row * N + col] = acc[i][j][r];
                }
    }
}

// ---------- 3b) 128x384-tile GEMM, v5: 32x32x16 MFMA (half the instructions,
// +15% pipe ceiling), keeping v4's best-so-far 2-region schedule ----------
// Grid 16x32 = 512 blocks = exactly 2 occupancy rounds (no tail).
// 8 waves (2M x 4N), per-wave 64x96 = 2(mb) x 3(nb) blocks of 32x32:
// acc[2][3] f32x16 = 96 AGPR. MFMA per K-tile per wave: 24 (vs 48 at 16x16).
// Fragment layout 32x32x16: A/B lane l holds row/col = l&31, k = (l>>5)*8..+8;
// C/D: col = l&31, row = (r&3) + 8*(r>>2) + 4*(l>>5), r in [0,16).
// chunk^(row&7) LDS swizzle stays conflict-free (every 8 consecutive lanes
// cover all 8 chunk slots).
// Region 1: ALL 20 ds_reads + stage B2(t+1),A(t+1)->p^1; 12 MFMA (ks0,1);
//           lgkmcnt(0) [WAR guard]; B_mid.
// Region 2: stage B0,B1(t+2)->p; 12 MFMA (ks2,3); vmcnt(4); B_end.
template<bool BF16OUT, bool ROPE>
__global__ __launch_bounds__(512, 2) void k_gemm384(const u16* __restrict__ Amat,
                                                    const u16* __restrict__ Bt,
                                                    void* __restrict__ Cout,
                                                    int M, int N, int K) {
    __shared__ __align__(16) u16 As[2][128 * 64];
    __shared__ __align__(16) u16 Bs[2][384 * 64];
    const int t = threadIdx.x;
    const int lane = t & 63, wave = t >> 6;
    const int l31 = lane & 31, half = lane >> 5;
    const int wr = wave >> 2, wc = wave & 3;          // 2M x 4N wave grid
    const int srow = lane >> 3;                        // 0..7
    const int sch = (lane & 7) ^ srow;                 // pre-swizzled global k-chunk

    // chunked XCD-aware swizzle for grid 16x32 (8 XCDs, each 4bx x 16by)
    int bx, by;
    if (gridDim.x == 16 && gridDim.y == 32) {
        int orig = blockIdx.y * gridDim.x + blockIdx.x;
        int xcd = orig & 7, loc = orig >> 3;           // loc 0..63
        int cx = xcd & 3, cy = xcd >> 2;
        bx = cx * 4 + (loc & 3);
        by = cy * 16 + (loc >> 2);
    } else {
        bx = blockIdx.x; by = blockIdx.y;
    }
    const size_t m0 = (size_t)by * 128, n0 = (size_t)bx * 384;

    const u16* Ab = Amat + m0 * (size_t)K;
    const u16* Bb = Bt + n0 * (size_t)K;
    const int NT = K >> 6;

    // stage 128 rows (2 x gl2lds/thread; LDS linear, global pre-swizzled)
    auto stage128 = [&](const u16* gbase, u16* lbase, int k0) {
        int rb0 = wave * 8;
        gl2lds16(gbase + (size_t)(rb0 + srow) * K + k0 + sch * 8, lbase + rb0 * 64);
        int rb1 = rb0 + 64;
        gl2lds16(gbase + (size_t)(rb1 + srow) * K + k0 + sch * 8, lbase + rb1 * 64);
    };

    f32x16 acc[2][3] = {};
    s16x8 af[2][4], bq[3][4];

    // ---- prologue: tile0 (B0,B1,B2,A) -> buf0 ; B0,B1(1) -> buf1 ; vmcnt(4) ----
    stage128(Bb,                   &Bs[0][0],        0);
    stage128(Bb + 128 * (size_t)K, &Bs[0][128 * 64], 0);
    stage128(Bb + 256 * (size_t)K, &Bs[0][256 * 64], 0);
    stage128(Ab,                   &As[0][0],        0);
    if (NT > 1) {
        stage128(Bb,                   &Bs[1][0],        64);
        stage128(Bb + 128 * (size_t)K, &Bs[1][128 * 64], 64);
        asm volatile("s_waitcnt vmcnt(4)" ::: "memory");   // tile0's 8 loads landed
    } else {
        asm volatile("s_waitcnt vmcnt(0)" ::: "memory");
    }
    __builtin_amdgcn_s_barrier();

    for (int kt = 0; kt < NT; ++kt) {
        const int p = kt & 1;

        // ===== region 1: all 20 reads; stage B2(t+1),A(t+1)->p^1; MFMA ks0,1 =====
#pragma unroll
        for (int ks = 0; ks < 2; ++ks) {
            int kc = ks * 2 + half;
#pragma unroll
            for (int mb = 0; mb < 2; ++mb) {
                int ra = wr * 64 + mb * 32 + l31;
                af[mb][ks] = *reinterpret_cast<const s16x8*>(&As[p][ra * 64 + (kc ^ (ra & 7)) * 8]);
            }
#pragma unroll
            for (int nb = 0; nb < 3; ++nb) {
                int rb = wc * 96 + nb * 32 + l31;
                bq[nb][ks] = *reinterpret_cast<const s16x8*>(&Bs[p][rb * 64 + (kc ^ (rb & 7)) * 8]);
            }
        }
        if (kt + 1 < NT) stage128(Bb + 256 * (size_t)K, &Bs[p ^ 1][256 * 64], (kt + 1) << 6);
#pragma unroll
        for (int ks = 2; ks < 4; ++ks) {
            int kc = ks * 2 + half;
#pragma unroll
            for (int mb = 0; mb < 2; ++mb) {
                int ra = wr * 64 + mb * 32 + l31;
                af[mb][ks] = *reinterpret_cast<const s16x8*>(&As[p][ra * 64 + (kc ^ (ra & 7)) * 8]);
            }
#pragma unroll
            for (int nb = 0; nb < 3; ++nb) {
                int rb = wc * 96 + nb * 32 + l31;
                bq[nb][ks] = *reinterpret_cast<const s16x8*>(&Bs[p][rb * 64 + (kc ^ (rb & 7)) * 8]);
            }
        }
        if (kt + 1 < NT) stage128(Ab, &As[p ^ 1][0], (kt + 1) << 6);

        __builtin_amdgcn_s_setprio(1);
#pragma unroll
        for (int ks = 0; ks < 2; ++ks)
#pragma unroll
            for (int mb = 0; mb < 2; ++mb)
#pragma unroll
                for (int nb = 0; nb < 3; ++nb)
                    acc[mb][nb] = __builtin_amdgcn_mfma_f32_32x32x16_bf16(af[mb][ks], bq[nb][ks], acc[mb][nb], 0, 0, 0);
        __builtin_amdgcn_s_setprio(0);

        asm volatile("s_waitcnt lgkmcnt(0)" ::: "memory");   // ~free; WAR guard
        __builtin_amdgcn_s_barrier();                        // B_mid: p reads done

        // ===== region 2: stage B0,B1(t+2)->p; MFMA ks2,3; counted vmcnt; B_end =====
        if (kt + 2 < NT) {
            stage128(Bb,                   &Bs[p][0],        (kt + 2) << 6);
            stage128(Bb + 128 * (size_t)K, &Bs[p][128 * 64], (kt + 2) << 6);
        }
        __builtin_amdgcn_s_setprio(1);
#pragma unroll
        for (int ks = 2; ks < 4; ++ks)
#pragma unroll
            for (int mb = 0; mb < 2; ++mb)
#pragma unroll
                for (int nb = 0; nb < 3; ++nb)
                    acc[mb][nb] = __builtin_amdgcn_mfma_f32_32x32x16_bf16(af[mb][ks], bq[nb][ks], acc[mb][nb], 0, 0, 0);
        __builtin_amdgcn_s_setprio(0);
        if (kt + 2 < NT) {
            asm volatile("s_waitcnt vmcnt(4)" ::: "memory"); // retires tile t+1 exactly
        } else {
            asm volatile("s_waitcnt vmcnt(0)" ::: "memory");
        }
        __builtin_amdgcn_s_barrier();                        // B_end
    }

    // ---- epilogue (32x32 C/D layout: col = l31, row = (r&3)+8*(r>>2)+4*half) ----
    if (ROPE) {
        float invf[3];
#pragma unroll
        for (int nb = 0; nb < 3; ++nb) {
            int pi = ((int)(n0 + wc * 96 + nb * 32 + l31) & 127) >> 1;
            invf[nb] = __expf(-0.14391156831f * (float)pi);
        }
#pragma unroll
        for (int mb = 0; mb < 2; ++mb)
#pragma unroll
            for (int nb = 0; nb < 3; ++nb) {
                size_t colbase = n0 + wc * 96 + nb * 32;
                size_t col = colbase + l31;
                if (colbase < 4096) {
#pragma unroll
                    for (int r = 0; r < 16; ++r) {
                        float v = acc[mb][nb][r];
                        float pv = __shfl_xor(v, 1);
                        size_t row = m0 + wr * 64 + mb * 32 + (r & 3) + 8 * (r >> 2) + 4 * half;
                        float f = (float)(int)(row & 2047) * invf[nb];
                        float sn, cs;
                        __sincosf(f, &sn, &cs);
                        float res = (lane & 1) ? fmaf(pv, sn, v * cs) : fmaf(v, cs, -pv * sn);
                        ((u16*)Cout)[row * N + col] = f32_to_bf16_rne(res);
                    }
                } else {
#pragma unroll
                    for (int r = 0; r < 16; ++r) {
                        size_t row = m0 + wr * 64 + mb * 32 + (r & 3) + 8 * (r >> 2) + 4 * half;
                        ((u16*)Cout)[row * N + col] = f32_to_bf16_rne(acc[mb][nb][r]);
                    }
                }
            }
    } else {
#pragma unroll
        for (int mb = 0; mb < 2; ++mb)
#pragma unroll
            for (int nb = 0; nb < 3; ++nb) {
                size_t col = n0 + wc * 96 + nb * 32 + l31;
#pragma unroll
                for (int r = 0; r < 16; ++r) {
                    size_t row = m0 + wr * 64 + mb * 32 + (r & 3) + 8 * (r >> 2) + 4 * half;
                    if (BF16OUT)
                        ((u16*)Cout)[row * N + col] = f32_to_bf16_rne(acc[mb][nb][r]);
                    else
                        ((float*)Cout)[row * N + col] = acc[mb][nb][r];
                }
            }
    }
}

// ---------- 4) V -> V^T ----------
__global__ __launch_bounds__(256) void k_transpose_v(const u16* __restrict__ qkv,
                                                     u16* __restrict__ vt) {
    __shared__ u16 TT[128 * 130];
    const int t = threadIdx.x;
    const int st = blockIdx.x;
    const int bh = blockIdx.y;
    const int b = bh >> 4, h = bh & 15;
    const u16* src = qkv + (size_t)b * 2048 * 6144 + 4096 + (size_t)h * 128;
    const int tr = t >> 4, tc = t & 15;
    s16x8 v[8];
#pragma unroll
    for (int u = 0; u < 8; ++u) {
        int s = u * 16 + tr;
        v[u] = *reinterpret_cast<const s16x8*>(src + (size_t)(st * 128 + s) * 6144 + tc * 8);
    }
#pragma unroll
    for (int u = 0; u < 8; ++u) {
        int s = u * 16 + tr;
#pragma unroll
        for (int e = 0; e < 8; ++e)
            TT[(tc * 8 + e) * 130 + s] = (u16)v[u][e];
    }
    __syncthreads();
    u16* dst = vt + (size_t)bh * 128 * 2048 + st * 128;
#pragma unroll
    for (int u = 0; u < 8; ++u) {
        int d = u * 16 + tr;
        int s0 = tc * 8;
        s16x8 o;
#pragma unroll
        for (int e = 0; e < 8; ++e) o[e] = (short)TT[d * 130 + s0 + e];
        *reinterpret_cast<s16x8*>(dst + (size_t)d * 2048 + s0) = o;
    }
}

// ---------- 5) flash attention (unchanged — protected win) ----------
__global__ __launch_bounds__(512, 4) void k_flash(const u16* __restrict__ qkv,
                                                  const u16* __restrict__ vt,
                                                  u16* __restrict__ out) {
    __shared__ __align__(16) u16 KS[128 * 136];
    __shared__ __align__(16) u16 VS[128 * 136];
    const int t = threadIdx.x, lane = t & 63, wave = t >> 6;
    const int m16 = lane & 15, qd = lane >> 4;
    const int bh = blockIdx.y, b = bh >> 4, h = bh & 15;
    const int q0 = blockIdx.x * 128;
    const u16* Qg = qkv + (size_t)b * 2048 * 6144 + (size_t)h * 128;
    const u16* Kg = Qg + 2048;
    const u16* Vtg = vt + (size_t)bh * 128 * 2048;
    const float C2 = 0.12751743f;

    int srow[4], scol[4], pi0[4];
#pragma unroll
    for (int ci = 0; ci < 4; ++ci) {
        int idx = ci * 512 + t;
        int row = idx >> 4, c = idx & 15;
        srow[ci] = row;
        scol[ci] = c * 8;
        pi0[ci] = 32 * (c >> 2) + 16 * (c & 1) + 4 * ((c >> 1) & 1);
    }

    s16x8 qf[4];
#pragma unroll
    for (int kc = 0; kc < 4; ++kc)
        qf[kc] = *reinterpret_cast<const s16x8*>(
            Qg + (size_t)(q0 + wave * 16 + m16) * 6144 + kc * 32 + qd * 8);

    f32x4 accO[8] = {};
    float mrow = -1e30f, lrow = 0.f;

    for (int kt = 0; kt < 16; ++kt) {
        const int s0 = kt * 128;
        s16x8 kreg[4], vreg[4];
#pragma unroll
        for (int ci = 0; ci < 4; ++ci) {
            kreg[ci] = *reinterpret_cast<const s16x8*>(
                Kg + (size_t)(s0 + srow[ci]) * 6144 + scol[ci]);
            vreg[ci] = *reinterpret_cast<const s16x8*>(
                Vtg + (size_t)srow[ci] * 2048 + s0 + scol[ci]);
        }
        __syncthreads();
#pragma unroll
        for (int ci = 0; ci < 4; ++ci) {
            *reinterpret_cast<s16x8*>(&KS[srow[ci] * 136 + scol[ci]]) = kreg[ci];
            s16x4 lo = __builtin_shufflevector(vreg[ci], vreg[ci], 0, 1, 2, 3);
            s16x4 hi = __builtin_shufflevector(vreg[ci], vreg[ci], 4, 5, 6, 7);
            *reinterpret_cast<s16x4*>(&VS[srow[ci] * 136 + pi0[ci]]) = lo;
            *reinterpret_cast<s16x4*>(&VS[srow[ci] * 136 + pi0[ci] + 8]) = hi;
        }
        __syncthreads();

        f32x4 accS[8] = {};
#pragma unroll
        for (int kc = 0; kc < 4; ++kc)
#pragma unroll
            for (int nj = 0; nj < 8; ++nj) {
                s16x8 kf = *reinterpret_cast<const s16x8*>(
                    &KS[(nj * 16 + m16) * 136 + (kc * 4 + qd) * 8]);
                accS[nj] = __builtin_amdgcn_mfma_f32_16x16x32_bf16(kf, qf[kc], accS[nj], 0, 0, 0);
            }

        float mx = accS[0][0];
#pragma unroll
        for (int nj = 0; nj < 8; ++nj)
#pragma unroll
            for (int r = 0; r < 4; ++r) mx = fmaxf(mx, accS[nj][r]);
        mx *= C2;
        mx = fmaxf(mx, __shfl_xor(mx, 16));
        mx = fmaxf(mx, __shfl_xor(mx, 32));
        float mn = fmaxf(mrow, mx);
        float alpha = __builtin_amdgcn_exp2f(mrow - mn);
        mrow = mn;
        float ls = 0.f;
        s16x4 pk[8];
#pragma unroll
        for (int nj = 0; nj < 8; ++nj) {
            float p0 = __builtin_amdgcn_exp2f(fmaf(accS[nj][0], C2, -mn));
            float p1 = __builtin_amdgcn_exp2f(fmaf(accS[nj][1], C2, -mn));
            float p2 = __builtin_amdgcn_exp2f(fmaf(accS[nj][2], C2, -mn));
            float p3 = __builtin_amdgcn_exp2f(fmaf(accS[nj][3], C2, -mn));
            ls += (p0 + p1) + (p2 + p3);
            u32 lo = pack_bf16_rhu(p0, p1);
            u32 hi = pack_bf16_rhu(p2, p3);
            uint2 pr = make_uint2(lo, hi);
            pk[nj] = __builtin_bit_cast(s16x4, pr);
        }
        ls += __shfl_xor(ls, 16);
        ls += __shfl_xor(ls, 32);
        lrow = lrow * alpha + ls;
        float aO[4];
#pragma unroll
        for (int r = 0; r < 4; ++r) aO[r] = __shfl(alpha, qd * 4 + r);
#pragma unroll
        for (int dj = 0; dj < 8; ++dj)
#pragma unroll
            for (int r = 0; r < 4; ++r) accO[dj][r] *= aO[r];

#pragma unroll
        for (int kb = 0; kb < 4; ++kb) {
            s16x8 af = __builtin_shufflevector(pk[2 * kb], pk[2 * kb + 1],
                                               0, 1, 2, 3, 4, 5, 6, 7);
#pragma unroll
            for (int dj = 0; dj < 8; ++dj) {
                s16x8 vf = *reinterpret_cast<const s16x8*>(
                    &VS[(dj * 16 + m16) * 136 + kb * 32 + qd * 8]);
                accO[dj] = __builtin_amdgcn_mfma_f32_16x16x32_bf16(af, vf, accO[dj], 0, 0, 0);
            }
        }
    }
    float invl = 1.0f / lrow;
    float iv[4];
#pragma unroll
    for (int r = 0; r < 4; ++r) iv[r] = __shfl(invl, qd * 4 + r);
#pragma unroll
    for (int r = 0; r < 4; ++r) {
        size_t row = (size_t)b * 2048 + q0 + wave * 16 + qd * 4 + r;
#pragma unroll
        for (int dj = 0; dj < 8; ++dj)
            out[row * 2048 + h * 128 + dj * 16 + m16] =
                f32_to_bf16_rne(accO[dj][r] * iv[r]);
    }
}

// ---------- launch ----------
extern "C" void kernel_launch(void* const* d_in, const int* in_sizes, int n_in,
                              void* d_out, int out_size, void* d_ws, size_t ws_size,
                              hipStream_t stream) {
    const float* x     = (const float*)d_in[0];
    const float* W_qkv = (const float*)d_in[1];
    const float* W_out = (const float*)d_in[2];
    float* out = (float*)d_out;

    char* ws = (char*)d_ws;
    u16* xb   = (u16*)(ws);
    u16* Wqt  = (u16*)(ws + (16u << 20));
    u16* Wot  = (u16*)(ws + (40u << 20));
    u16* qkvb = (u16*)(ws + (48u << 20));
    u16* attn = (u16*)(ws + (96u << 20));
    u16* vtg  = (u16*)(ws + (112u << 20));

    k_cast<<<4096, 256, 0, stream>>>(x, xb);
    k_transpose_cast<<<dim3(96, 16), 256, 0, stream>>>(W_qkv, Wqt, 2048, 6144);
    k_transpose_cast<<<dim3(32, 16), 256, 0, stream>>>(W_out, Wot, 2048, 2048);
    k_gemm384<true, true><<<dim3(16, 32), 512, 0, stream>>>(xb, Wqt, qkvb, 4096, 6144, 2048);
    k_transpose_v<<<dim3(16, 32), 256, 0, stream>>>(qkvb, vtg);
    k_flash<<<dim3(16, 32), 512, 0, stream>>>(qkvb, vtg, attn);
    k_gemm_bt<false, false><<<dim3(16, 32), 256, 0, stream>>>(attn, Wot, out, 4096, 2048, 2048);
}

// Round 6
// 400.546 us; speedup vs baseline: 1.0365x; 1.0004x over previous
//
#include <hip/hip_runtime.h>
#include <math.h>

typedef float  f32x4  __attribute__((ext_vector_type(4)));
typedef short  s16x8 __attribute__((ext_vector_type(8)));
typedef short  s16x4 __attribute__((ext_vector_type(4)));
typedef unsigned short u16;
typedef unsigned int u32;

// ---------- bf16 helpers ----------
static __device__ __forceinline__ u16 f32_to_bf16_rne(float f) {
    u32 u = __builtin_bit_cast(u32, f);
    u32 r = u + 0x7fffu + ((u >> 16) & 1u);
    return (u16)(r >> 16);
}
static __device__ __forceinline__ u32 pack_bf16_rhu(float a, float b) {
    u32 ua = __builtin_bit_cast(u32, a);
    u32 ub = __builtin_bit_cast(u32, b);
    return ((ua + 0x8000u) >> 16) | ((ub + 0x8000u) & 0xffff0000u);
}
static __device__ __forceinline__ float bf16_to_f32(u16 h) {
    return __builtin_bit_cast(float, (u32)h << 16);
}

// async global->LDS 16B (lane-contiguous LDS dest ONLY; source is per-lane)
static __device__ __forceinline__ void gl2lds16(const void* g, void* l) {
    __builtin_amdgcn_global_load_lds(
        (const __attribute__((address_space(1))) u32*)g,
        (__attribute__((address_space(3))) u32*)l, 16, 0, 0);
}

// ---------- 1) cast fp32 -> bf16 ----------
__global__ __launch_bounds__(256) void k_cast(const float* __restrict__ in,
                                              u16* __restrict__ out) {
    int i = (blockIdx.x * 256 + threadIdx.x) * 8;
    float4 a = *reinterpret_cast<const float4*>(in + i);
    float4 b = *reinterpret_cast<const float4*>(in + i + 4);
    s16x8 o;
    o[0] = (short)f32_to_bf16_rne(a.x); o[1] = (short)f32_to_bf16_rne(a.y);
    o[2] = (short)f32_to_bf16_rne(a.z); o[3] = (short)f32_to_bf16_rne(a.w);
    o[4] = (short)f32_to_bf16_rne(b.x); o[5] = (short)f32_to_bf16_rne(b.y);
    o[6] = (short)f32_to_bf16_rne(b.z); o[7] = (short)f32_to_bf16_rne(b.w);
    *reinterpret_cast<s16x8*>(out + i) = o;
}

// ---------- 2) transpose + cast ----------
__global__ __launch_bounds__(256) void k_transpose_cast(const float* __restrict__ in,
                                                        u16* __restrict__ out,
                                                        int R, int C) {
    __shared__ float TT[64 * 130];
    const int t = threadIdx.x;
    const int ct = blockIdx.x, rt = blockIdx.y;
    const int tr = t >> 4;
    const int tc = t & 15;
    float4 v[8];
#pragma unroll
    for (int u = 0; u < 8; ++u) {
        int r = u * 16 + tr;
        v[u] = *reinterpret_cast<const float4*>(in + (size_t)(rt * 128 + r) * C + ct * 64 + tc * 4);
    }
#pragma unroll
    for (int u = 0; u < 8; ++u) {
        int r = u * 16 + tr;
        TT[(tc * 4 + 0) * 130 + r] = v[u].x;
        TT[(tc * 4 + 1) * 130 + r] = v[u].y;
        TT[(tc * 4 + 2) * 130 + r] = v[u].z;
        TT[(tc * 4 + 3) * 130 + r] = v[u].w;
    }
    __syncthreads();
#pragma unroll
    for (int u = 0; u < 4; ++u) {
        int oc = u * 16 + tr;
        int r0 = tc * 8;
        s16x8 o;
#pragma unroll
        for (int e = 0; e < 8; ++e)
            o[e] = (short)f32_to_bf16_rne(TT[oc * 130 + r0 + e]);
        *reinterpret_cast<s16x8*>(out + (size_t)(ct * 64 + oc) * R + rt * 128 + r0) = o;
    }
}

// ---------- 3a) 128x384-tile GEMM for QKV (v4 — best measured: 122.6us) ----------
// Grid 16x32 = 512 blocks = exactly 2 occupancy rounds (no tail).
// 8 waves (2M x 4N), per-wave 64x96: acc[4][6] = 96 AGPR -> 2 waves/SIMD.
// LDS: As[2][128*64] + Bs[2][384*64] = 128 KiB.
// Region1: all 20 ds_reads + stage B2(t+1),A(t+1)->p^1; 24 MFMA kh0;
//          lgkmcnt(0) [WAR]; B_mid.
// Region2: stage B0,B1(t+2)->p; 24 MFMA kh1; vmcnt(4); B_end.
template<bool BF16OUT, bool ROPE>
__global__ __launch_bounds__(512, 2) void k_gemm384(const u16* __restrict__ Amat,
                                                    const u16* __restrict__ Bt,
                                                    void* __restrict__ Cout,
                                                    int M, int N, int K) {
    __shared__ __align__(16) u16 As[2][128 * 64];
    __shared__ __align__(16) u16 Bs[2][384 * 64];
    const int t = threadIdx.x;
    const int lane = t & 63, wave = t >> 6;
    const int m16 = lane & 15, qd = lane >> 4;
    const int wr = wave >> 2, wc = wave & 3;          // 2M x 4N wave grid
    const int srow = lane >> 3;                        // 0..7
    const int sch = (lane & 7) ^ srow;                 // pre-swizzled global k-chunk

    // chunked XCD-aware swizzle for grid 16x32 (8 XCDs, each 4bx x 16by)
    int bx, by;
    if (gridDim.x == 16 && gridDim.y == 32) {
        int orig = blockIdx.y * gridDim.x + blockIdx.x;
        int xcd = orig & 7, loc = orig >> 3;           // loc 0..63
        int cx = xcd & 3, cy = xcd >> 2;
        bx = cx * 4 + (loc & 3);
        by = cy * 16 + (loc >> 2);
    } else {
        bx = blockIdx.x; by = blockIdx.y;
    }
    const size_t m0 = (size_t)by * 128, n0 = (size_t)bx * 384;

    const u16* Ab = Amat + m0 * (size_t)K;
    const u16* Bb = Bt + n0 * (size_t)K;
    const int NT = K >> 6;

    // stage 128 rows (2 x gl2lds/thread; LDS linear, global pre-swizzled)
    auto stage128 = [&](const u16* gbase, u16* lbase, int k0) {
        int rb0 = wave * 8;
        gl2lds16(gbase + (size_t)(rb0 + srow) * K + k0 + sch * 8, lbase + rb0 * 64);
        int rb1 = rb0 + 64;
        gl2lds16(gbase + (size_t)(rb1 + srow) * K + k0 + sch * 8, lbase + rb1 * 64);
    };

    f32x4 acc[4][6] = {};
    s16x8 af[4][2], bq[6][2];

    // ---- prologue: tile0 (B0,B1,B2,A) -> buf0 ; B0,B1(1) -> buf1 ; vmcnt(4) ----
    stage128(Bb,                   &Bs[0][0],        0);
    stage128(Bb + 128 * (size_t)K, &Bs[0][128 * 64], 0);
    stage128(Bb + 256 * (size_t)K, &Bs[0][256 * 64], 0);
    stage128(Ab,                   &As[0][0],        0);
    if (NT > 1) {
        stage128(Bb,                   &Bs[1][0],        64);
        stage128(Bb + 128 * (size_t)K, &Bs[1][128 * 64], 64);
        asm volatile("s_waitcnt vmcnt(4)" ::: "memory");   // tile0's 8 loads landed
    } else {
        asm volatile("s_waitcnt vmcnt(0)" ::: "memory");
    }
    __builtin_amdgcn_s_barrier();

    for (int kt = 0; kt < NT; ++kt) {
        const int p = kt & 1;

        // ===== region 1: all reads (kh0+kh1); stage B2(t+1),A(t+1)->p^1; MFMA kh0 =====
#pragma unroll
        for (int i = 0; i < 4; ++i) {
            int ra = wr * 64 + i * 16 + m16;
            af[i][0] = *reinterpret_cast<const s16x8*>(&As[p][ra * 64 + ((qd)     ^ (ra & 7)) * 8]);
        }
#pragma unroll
        for (int j = 0; j < 6; ++j) {
            int rb = wc * 96 + j * 16 + m16;
            bq[j][0] = *reinterpret_cast<const s16x8*>(&Bs[p][rb * 64 + ((qd)     ^ (rb & 7)) * 8]);
        }
        if (kt + 1 < NT) stage128(Bb + 256 * (size_t)K, &Bs[p ^ 1][256 * 64], (kt + 1) << 6);
#pragma unroll
        for (int i = 0; i < 4; ++i) {
            int ra = wr * 64 + i * 16 + m16;
            af[i][1] = *reinterpret_cast<const s16x8*>(&As[p][ra * 64 + ((4 + qd) ^ (ra & 7)) * 8]);
        }
#pragma unroll
        for (int j = 0; j < 6; ++j) {
            int rb = wc * 96 + j * 16 + m16;
            bq[j][1] = *reinterpret_cast<const s16x8*>(&Bs[p][rb * 64 + ((4 + qd) ^ (rb & 7)) * 8]);
        }
        if (kt + 1 < NT) stage128(Ab, &As[p ^ 1][0], (kt + 1) << 6);

        __builtin_amdgcn_s_setprio(1);
#pragma unroll
        for (int i = 0; i < 4; ++i)
#pragma unroll
            for (int j = 0; j < 6; ++j)
                acc[i][j] = __builtin_amdgcn_mfma_f32_16x16x32_bf16(af[i][0], bq[j][0], acc[i][j], 0, 0, 0);
        __builtin_amdgcn_s_setprio(0);

        asm volatile("s_waitcnt lgkmcnt(0)" ::: "memory");   // ~free; WAR guard
        __builtin_amdgcn_s_barrier();                        // B_mid: p reads done

        // ===== region 2: stage B0,B1(t+2)->p; MFMA kh1; counted vmcnt; B_end =====
        if (kt + 2 < NT) {
            stage128(Bb,                   &Bs[p][0],        (kt + 2) << 6);
            stage128(Bb + 128 * (size_t)K, &Bs[p][128 * 64], (kt + 2) << 6);
        }
        __builtin_amdgcn_s_setprio(1);
#pragma unroll
        for (int i = 0; i < 4; ++i)
#pragma unroll
            for (int j = 0; j < 6; ++j)
                acc[i][j] = __builtin_amdgcn_mfma_f32_16x16x32_bf16(af[i][1], bq[j][1], acc[i][j], 0, 0, 0);
        __builtin_amdgcn_s_setprio(0);
        if (kt + 2 < NT) {
            asm volatile("s_waitcnt vmcnt(4)" ::: "memory"); // retires tile t+1 exactly
        } else {
            asm volatile("s_waitcnt vmcnt(0)" ::: "memory");
        }
        __builtin_amdgcn_s_barrier();                        // B_end
    }

    // ---- epilogue (per-16-col ROPE guard: 384 does not divide 4096) ----
    if (ROPE) {
        float invf[6];
#pragma unroll
        for (int j = 0; j < 6; ++j) {
            int pi = ((int)(n0 + wc * 96 + j * 16 + m16) & 127) >> 1;
            invf[j] = __expf(-0.14391156831f * (float)pi);
        }
#pragma unroll
        for (int i = 0; i < 4; ++i)
#pragma unroll
            for (int j = 0; j < 6; ++j) {
                size_t colbase = n0 + wc * 96 + j * 16;
                if (colbase < 4096) {
#pragma unroll
                    for (int r = 0; r < 4; ++r) {
                        float v = acc[i][j][r];
                        float pv = __shfl_xor(v, 1);
                        size_t row = m0 + wr * 64 + i * 16 + qd * 4 + r;
                        float f = (float)(int)(row & 2047) * invf[j];
                        float sn, cs;
                        __sincosf(f, &sn, &cs);
                        float res = (m16 & 1) ? fmaf(pv, sn, v * cs) : fmaf(v, cs, -pv * sn);
                        ((u16*)Cout)[row * N + colbase + m16] = f32_to_bf16_rne(res);
                    }
                } else {
#pragma unroll
                    for (int r = 0; r < 4; ++r) {
                        size_t row = m0 + wr * 64 + i * 16 + qd * 4 + r;
                        ((u16*)Cout)[row * N + colbase + m16] = f32_to_bf16_rne(acc[i][j][r]);
                    }
                }
            }
    } else {
#pragma unroll
        for (int i = 0; i < 4; ++i)
#pragma unroll
            for (int j = 0; j < 6; ++j)
#pragma unroll
                for (int r = 0; r < 4; ++r) {
                    size_t row = m0 + wr * 64 + i * 16 + qd * 4 + r;
                    size_t col = n0 + wc * 96 + j * 16 + m16;
                    if (BF16OUT)
                        ((u16*)Cout)[row * N + col] = f32_to_bf16_rne(acc[i][j][r]);
                    else
                        ((float*)Cout)[row * N + col] = acc[i][j][r];
                }
    }
}

// ---------- 3b) NEW: out-projection GEMM, 128x256 tile, v4 schedule ----------
// M=4096, N=2048, K=2048. Grid (8,32) = 256 blocks = exactly 1 round, no tail.
// 8 waves (2M x 4N), per-wave 64x64: acc[4][4] = 64 AGPR. LDS 96 KiB dbuf.
// 3 stage-units/K-tile (A, B0, B1). Ledger:
//   prologue: A,B0,B1(0)->buf0 [6 loads] + A,B0(1)->buf1 [4]; vmcnt(4).
//   region1(t): 16 ds_reads; stage B1(t+1)->p^1 [2]; 16 MFMA kh0;
//               lgkmcnt(0); B_mid.
//   region2(t): stage A,B0(t+2)->p [4]; 16 MFMA kh1; vmcnt(4)  [10 out-
//               standing -> retires 6 = tile t+1 exactly, 4 in flight]; B_end.
__global__ __launch_bounds__(512, 2) void k_gemmo(const u16* __restrict__ Amat,
                                                  const u16* __restrict__ Bt,
                                                  float* __restrict__ Cout,
                                                  int M, int N, int K) {
    __shared__ __align__(16) u16 As[2][128 * 64];
    __shared__ __align__(16) u16 Bs[2][256 * 64];
    const int t = threadIdx.x;
    const int lane = t & 63, wave = t >> 6;
    const int m16 = lane & 15, qd = lane >> 4;
    const int wr = wave >> 2, wc = wave & 3;          // 2M x 4N wave grid
    const int srow = lane >> 3;                        // 0..7
    const int sch = (lane & 7) ^ srow;                 // pre-swizzled global k-chunk

    // chunked XCD-aware swizzle for grid 8x32 (8 XCDs, each 4bx x 8by)
    int bx, by;
    if (gridDim.x == 8 && gridDim.y == 32) {
        int orig = blockIdx.y * gridDim.x + blockIdx.x;
        int xcd = orig & 7, loc = orig >> 3;           // loc 0..31
        int cx = xcd & 1, cy = xcd >> 1;               // 2 x-chunks, 4 y-chunks
        bx = cx * 4 + (loc & 3);
        by = cy * 8 + (loc >> 2);
    } else {
        bx = blockIdx.x; by = blockIdx.y;
    }
    const size_t m0 = (size_t)by * 128, n0 = (size_t)bx * 256;

    const u16* Ab = Amat + m0 * (size_t)K;
    const u16* Bb = Bt + n0 * (size_t)K;
    const int NT = K >> 6;

    auto stage128 = [&](const u16* gbase, u16* lbase, int k0) {
        int rb0 = wave * 8;
        gl2lds16(gbase + (size_t)(rb0 + srow) * K + k0 + sch * 8, lbase + rb0 * 64);
        int rb1 = rb0 + 64;
        gl2lds16(gbase + (size_t)(rb1 + srow) * K + k0 + sch * 8, lbase + rb1 * 64);
    };

    f32x4 acc[4][4] = {};
    s16x8 af[4][2], bq[4][2];

    // ---- prologue ----
    stage128(Ab,                   &As[0][0],        0);
    stage128(Bb,                   &Bs[0][0],        0);
    stage128(Bb + 128 * (size_t)K, &Bs[0][128 * 64], 0);
    if (NT > 1) {
        stage128(Ab,               &As[1][0],        64);
        stage128(Bb,               &Bs[1][0],        64);
        asm volatile("s_waitcnt vmcnt(4)" ::: "memory");   // tile0's 6 loads landed
    } else {
        asm volatile("s_waitcnt vmcnt(0)" ::: "memory");
    }
    __builtin_amdgcn_s_barrier();

    for (int kt = 0; kt < NT; ++kt) {
        const int p = kt & 1;

        // ===== region 1: 16 reads; stage B1(t+1)->p^1; MFMA kh0 =====
#pragma unroll
        for (int i = 0; i < 4; ++i) {
            int ra = wr * 64 + i * 16 + m16;
            af[i][0] = *reinterpret_cast<const s16x8*>(&As[p][ra * 64 + ((qd)     ^ (ra & 7)) * 8]);
        }
#pragma unroll
        for (int j = 0; j < 4; ++j) {
            int rb = wc * 64 + j * 16 + m16;
            bq[j][0] = *reinterpret_cast<const s16x8*>(&Bs[p][rb * 64 + ((qd)     ^ (rb & 7)) * 8]);
        }
        if (kt + 1 < NT) stage128(Bb + 128 * (size_t)K, &Bs[p ^ 1][128 * 64], (kt + 1) << 6);
#pragma unroll
        for (int i = 0; i < 4; ++i) {
            int ra = wr * 64 + i * 16 + m16;
            af[i][1] = *reinterpret_cast<const s16x8*>(&As[p][ra * 64 + ((4 + qd) ^ (ra & 7)) * 8]);
        }
#pragma unroll
        for (int j = 0; j < 4; ++j) {
            int rb = wc * 64 + j * 16 + m16;
            bq[j][1] = *reinterpret_cast<const s16x8*>(&Bs[p][rb * 64 + ((4 + qd) ^ (rb & 7)) * 8]);
        }

        __builtin_amdgcn_s_setprio(1);
#pragma unroll
        for (int i = 0; i < 4; ++i)
#pragma unroll
            for (int j = 0; j < 4; ++j)
                acc[i][j] = __builtin_amdgcn_mfma_f32_16x16x32_bf16(af[i][0], bq[j][0], acc[i][j], 0, 0, 0);
        __builtin_amdgcn_s_setprio(0);

        asm volatile("s_waitcnt lgkmcnt(0)" ::: "memory");   // WAR guard
        __builtin_amdgcn_s_barrier();                        // B_mid

        // ===== region 2: stage A,B0(t+2)->p; MFMA kh1; counted vmcnt; B_end =====
        if (kt + 2 < NT) {
            stage128(Ab, &As[p][0], (kt + 2) << 6);
            stage128(Bb, &Bs[p][0], (kt + 2) << 6);
        }
        __builtin_amdgcn_s_setprio(1);
#pragma unroll
        for (int i = 0; i < 4; ++i)
#pragma unroll
            for (int j = 0; j < 4; ++j)
                acc[i][j] = __builtin_amdgcn_mfma_f32_16x16x32_bf16(af[i][1], bq[j][1], acc[i][j], 0, 0, 0);
        __builtin_amdgcn_s_setprio(0);
        if (kt + 2 < NT) {
            asm volatile("s_waitcnt vmcnt(4)" ::: "memory"); // retires tile t+1 exactly
        } else {
            asm volatile("s_waitcnt vmcnt(0)" ::: "memory");
        }
        __builtin_amdgcn_s_barrier();                        // B_end
    }

    // ---- epilogue: fp32 store ----
#pragma unroll
    for (int i = 0; i < 4; ++i)
#pragma unroll
        for (int j = 0; j < 4; ++j)
#pragma unroll
            for (int r = 0; r < 4; ++r) {
                size_t row = m0 + wr * 64 + i * 16 + qd * 4 + r;
                size_t col = n0 + wc * 64 + j * 16 + m16;
                Cout[row * N + col] = acc[i][j][r];
            }
}

// ---------- 4) V -> V^T ----------
__global__ __launch_bounds__(256) void k_transpose_v(const u16* __restrict__ qkv,
                                                     u16* __restrict__ vt) {
    __shared__ u16 TT[128 * 130];
    const int t = threadIdx.x;
    const int st = blockIdx.x;
    const int bh = blockIdx.y;
    const int b = bh >> 4, h = bh & 15;
    const u16* src = qkv + (size_t)b * 2048 * 6144 + 4096 + (size_t)h * 128;
    const int tr = t >> 4, tc = t & 15;
    s16x8 v[8];
#pragma unroll
    for (int u = 0; u < 8; ++u) {
        int s = u * 16 + tr;
        v[u] = *reinterpret_cast<const s16x8*>(src + (size_t)(st * 128 + s) * 6144 + tc * 8);
    }
#pragma unroll
    for (int u = 0; u < 8; ++u) {
        int s = u * 16 + tr;
#pragma unroll
        for (int e = 0; e < 8; ++e)
            TT[(tc * 8 + e) * 130 + s] = (u16)v[u][e];
    }
    __syncthreads();
    u16* dst = vt + (size_t)bh * 128 * 2048 + st * 128;
#pragma unroll
    for (int u = 0; u < 8; ++u) {
        int d = u * 16 + tr;
        int s0 = tc * 8;
        s16x8 o;
#pragma unroll
        for (int e = 0; e < 8; ++e) o[e] = (short)TT[d * 130 + s0 + e];
        *reinterpret_cast<s16x8*>(dst + (size_t)d * 2048 + s0) = o;
    }
}

// ---------- 5) flash attention (unchanged — protected win) ----------
__global__ __launch_bounds__(512, 4) void k_flash(const u16* __restrict__ qkv,
                                                  const u16* __restrict__ vt,
                                                  u16* __restrict__ out) {
    __shared__ __align__(16) u16 KS[128 * 136];
    __shared__ __align__(16) u16 VS[128 * 136];
    const int t = threadIdx.x, lane = t & 63, wave = t >> 6;
    const int m16 = lane & 15, qd = lane >> 4;
    const int bh = blockIdx.y, b = bh >> 4, h = bh & 15;
    const int q0 = blockIdx.x * 128;
    const u16* Qg = qkv + (size_t)b * 2048 * 6144 + (size_t)h * 128;
    const u16* Kg = Qg + 2048;
    const u16* Vtg = vt + (size_t)bh * 128 * 2048;
    const float C2 = 0.12751743f;

    int srow[4], scol[4], pi0[4];
#pragma unroll
    for (int ci = 0; ci < 4; ++ci) {
        int idx = ci * 512 + t;
        int row = idx >> 4, c = idx & 15;
        srow[ci] = row;
        scol[ci] = c * 8;
        pi0[ci] = 32 * (c >> 2) + 16 * (c & 1) + 4 * ((c >> 1) & 1);
    }

    s16x8 qf[4];
#pragma unroll
    for (int kc = 0; kc < 4; ++kc)
        qf[kc] = *reinterpret_cast<const s16x8*>(
            Qg + (size_t)(q0 + wave * 16 + m16) * 6144 + kc * 32 + qd * 8);

    f32x4 accO[8] = {};
    float mrow = -1e30f, lrow = 0.f;

    for (int kt = 0; kt < 16; ++kt) {
        const int s0 = kt * 128;
        s16x8 kreg[4], vreg[4];
#pragma unroll
        for (int ci = 0; ci < 4; ++ci) {
            kreg[ci] = *reinterpret_cast<const s16x8*>(
                Kg + (size_t)(s0 + srow[ci]) * 6144 + scol[ci]);
            vreg[ci] = *reinterpret_cast<const s16x8*>(
                Vtg + (size_t)srow[ci] * 2048 + s0 + scol[ci]);
        }
        __syncthreads();
#pragma unroll
        for (int ci = 0; ci < 4; ++ci) {
            *reinterpret_cast<s16x8*>(&KS[srow[ci] * 136 + scol[ci]]) = kreg[ci];
            s16x4 lo = __builtin_shufflevector(vreg[ci], vreg[ci], 0, 1, 2, 3);
            s16x4 hi = __builtin_shufflevector(vreg[ci], vreg[ci], 4, 5, 6, 7);
            *reinterpret_cast<s16x4*>(&VS[srow[ci] * 136 + pi0[ci]]) = lo;
            *reinterpret_cast<s16x4*>(&VS[srow[ci] * 136 + pi0[ci] + 8]) = hi;
        }
        __syncthreads();

        f32x4 accS[8] = {};
#pragma unroll
        for (int kc = 0; kc < 4; ++kc)
#pragma unroll
            for (int nj = 0; nj < 8; ++nj) {
                s16x8 kf = *reinterpret_cast<const s16x8*>(
                    &KS[(nj * 16 + m16) * 136 + (kc * 4 + qd) * 8]);
                accS[nj] = __builtin_amdgcn_mfma_f32_16x16x32_bf16(kf, qf[kc], accS[nj], 0, 0, 0);
            }

        float mx = accS[0][0];
#pragma unroll
        for (int nj = 0; nj < 8; ++nj)
#pragma unroll
            for (int r = 0; r < 4; ++r) mx = fmaxf(mx, accS[nj][r]);
        mx *= C2;
        mx = fmaxf(mx, __shfl_xor(mx, 16));
        mx = fmaxf(mx, __shfl_xor(mx, 32));
        float mn = fmaxf(mrow, mx);
        float alpha = __builtin_amdgcn_exp2f(mrow - mn);
        mrow = mn;
        float ls = 0.f;
        s16x4 pk[8];
#pragma unroll
        for (int nj = 0; nj < 8; ++nj) {
            float p0 = __builtin_amdgcn_exp2f(fmaf(accS[nj][0], C2, -mn));
            float p1 = __builtin_amdgcn_exp2f(fmaf(accS[nj][1], C2, -mn));
            float p2 = __builtin_amdgcn_exp2f(fmaf(accS[nj][2], C2, -mn));
            float p3 = __builtin_amdgcn_exp2f(fmaf(accS[nj][3], C2, -mn));
            ls += (p0 + p1) + (p2 + p3);
            u32 lo = pack_bf16_rhu(p0, p1);
            u32 hi = pack_bf16_rhu(p2, p3);
            uint2 pr = make_uint2(lo, hi);
            pk[nj] = __builtin_bit_cast(s16x4, pr);
        }
        ls += __shfl_xor(ls, 16);
        ls += __shfl_xor(ls, 32);
        lrow = lrow * alpha + ls;
        float aO[4];
#pragma unroll
        for (int r = 0; r < 4; ++r) aO[r] = __shfl(alpha, qd * 4 + r);
#pragma unroll
        for (int dj = 0; dj < 8; ++dj)
#pragma unroll
            for (int r = 0; r < 4; ++r) accO[dj][r] *= aO[r];

#pragma unroll
        for (int kb = 0; kb < 4; ++kb) {
            s16x8 af = __builtin_shufflevector(pk[2 * kb], pk[2 * kb + 1],
                                               0, 1, 2, 3, 4, 5, 6, 7);
#pragma unroll
            for (int dj = 0; dj < 8; ++dj) {
                s16x8 vf = *reinterpret_cast<const s16x8*>(
                    &VS[(dj * 16 + m16) * 136 + kb * 32 + qd * 8]);
                accO[dj] = __builtin_amdgcn_mfma_f32_16x16x32_bf16(af, vf, accO[dj], 0, 0, 0);
            }
        }
    }
    float invl = 1.0f / lrow;
    float iv[4];
#pragma unroll
    for (int r = 0; r < 4; ++r) iv[r] = __shfl(invl, qd * 4 + r);
#pragma unroll
    for (int r = 0; r < 4; ++r) {
        size_t row = (size_t)b * 2048 + q0 + wave * 16 + qd * 4 + r;
#pragma unroll
        for (int dj = 0; dj < 8; ++dj)
            out[row * 2048 + h * 128 + dj * 16 + m16] =
                f32_to_bf16_rne(accO[dj][r] * iv[r]);
    }
}

// ---------- launch ----------
extern "C" void kernel_launch(void* const* d_in, const int* in_sizes, int n_in,
                              void* d_out, int out_size, void* d_ws, size_t ws_size,
                              hipStream_t stream) {
    const float* x     = (const float*)d_in[0];
    const float* W_qkv = (const float*)d_in[1];
    const float* W_out = (const float*)d_in[2];
    float* out = (float*)d_out;

    char* ws = (char*)d_ws;
    u16* xb   = (u16*)(ws);
    u16* Wqt  = (u16*)(ws + (16u << 20));
    u16* Wot  = (u16*)(ws + (40u << 20));
    u16* qkvb = (u16*)(ws + (48u << 20));
    u16* attn = (u16*)(ws + (96u << 20));
    u16* vtg  = (u16*)(ws + (112u << 20));

    k_cast<<<4096, 256, 0, stream>>>(x, xb);
    k_transpose_cast<<<dim3(96, 16), 256, 0, stream>>>(W_qkv, Wqt, 2048, 6144);
    k_transpose_cast<<<dim3(32, 16), 256, 0, stream>>>(W_out, Wot, 2048, 2048);
    k_gemm384<true, true><<<dim3(16, 32), 512, 0, stream>>>(xb, Wqt, qkvb, 4096, 6144, 2048);
    k_transpose_v<<<dim3(16, 32), 256, 0, stream>>>(qkvb, vtg);
    k_flash<<<dim3(16, 32), 512, 0, stream>>>(qkvb, vtg, attn);
    k_gemmo<<<dim3(8, 32), 512, 0, stream>>>(attn, Wot, out, 4096, 2048, 2048);
}